// Round 4
// baseline (676.572 us; speedup 1.0000x reference)
//
#include <hip/hip_runtime.h>
#include <hip/hip_cooperative_groups.h>
#include <cmath>

namespace cg = cooperative_groups;

// ---------------------------------------------------------------------------
// StructuralAttentionLayer on MI355X (gfx950)
// N=50000, E=800000, D=128, H=8, DK=16
// Round 3: slot*head attention layout (8 edges/wave-iter, in-lane 16-dim dot,
//          no online max), cooperative single-kernel CSR build.
// ---------------------------------------------------------------------------

typedef short v8s __attribute__((ext_vector_type(8)));   // 8 bf16 (4 VGPRs)
typedef float v4f __attribute__((ext_vector_type(4)));   // 4 fp32 acc

__device__ __forceinline__ float gelu_exact(float x) {
    return 0.5f * x * (1.0f + erff(x * 0.70710678118654752440f));
}

__device__ __forceinline__ unsigned short f2bf(float f) {
    unsigned int u = __float_as_uint(f);
    u = (u + 0x7fffu + ((u >> 16) & 1u)) >> 16;
    return (unsigned short)u;
}

__device__ __forceinline__ float2 bf2_to_f2(unsigned int u) {
    float2 r;
    r.x = __uint_as_float(u << 16);
    r.y = __uint_as_float(u & 0xffff0000u);
    return r;
}

// ---- CSR build: one cooperative kernel -------------------------------------
// phases: zero cnt -> hist -> block scans -> top scan -> add/cursor -> scatter

__global__ __launch_bounds__(256)
void csr_kernel(const int* __restrict__ src, const int* __restrict__ dst,
                int* __restrict__ cnt, int* __restrict__ offs,
                int* __restrict__ bsum, int* __restrict__ esrc,
                int N, int E) {
    cg::grid_group grid = cg::this_grid();
    __shared__ int ws[4];
    const int t = threadIdx.x, wid = t >> 6, lane = t & 63;
    const int nb = gridDim.x;
    const int gid = blockIdx.x * 256 + t;
    const int gsz = nb * 256;

    // phase 0: zero counts
    for (int i = gid; i < N; i += gsz) cnt[i] = 0;
    grid.sync();

    // phase 1: histogram of dst
    for (int e = gid; e < E; e += gsz) atomicAdd(&cnt[dst[e]], 1);
    grid.sync();

    // phase 2: block-local exclusive scans over 256-chunks
    const int nchunk = (N + 255) / 256;
    for (int c = blockIdx.x; c < nchunk; c += nb) {
        int i = c * 256 + t;
        int v = (i < N) ? cnt[i] : 0;
        int incl = v;
        #pragma unroll
        for (int off = 1; off < 64; off <<= 1) {
            int u = __shfl_up(incl, off, 64);
            if (lane >= off) incl += u;
        }
        if (lane == 63) ws[wid] = incl;
        __syncthreads();
        int prefix = 0, tot = 0;
        #pragma unroll
        for (int w = 0; w < 4; ++w) {
            int s = ws[w];
            if (w < wid) prefix += s;
            tot += s;
        }
        if (i < N) offs[i] = prefix + incl - v;
        if (t == 0) bsum[c] = tot;
        __syncthreads();
    }
    grid.sync();

    // phase 3: top-level scan of block sums (nchunk <= 256), block 0 only
    if (blockIdx.x == 0) {
        int v = (t < nchunk) ? bsum[t] : 0;
        int incl = v;
        #pragma unroll
        for (int off = 1; off < 64; off <<= 1) {
            int u = __shfl_up(incl, off, 64);
            if (lane >= off) incl += u;
        }
        if (lane == 63) ws[wid] = incl;
        __syncthreads();
        int prefix = 0;
        #pragma unroll
        for (int w = 0; w < 4; ++w)
            if (w < wid) prefix += ws[w];
        if (t < nchunk) bsum[t] = prefix + incl - v;
    }
    grid.sync();

    // phase 4: add block offsets; init cursor (reuse cnt)
    for (int c = blockIdx.x; c < nchunk; c += nb) {
        int i = c * 256 + t;
        if (i < N) {
            int o = offs[i] + bsum[c];
            offs[i] = o;
            cnt[i] = o;
        }
    }
    if (gid == 0) offs[N] = E;
    grid.sync();

    // phase 5: scatter src ids by dst
    for (int e = gid; e < E; e += gsz) {
        int p = atomicAdd(&cnt[dst[e]], 1);
        esrc[p] = src[e];
    }
}

// ---- prep: weight transposes (fp32 -> bf16, [col][k]) + bias concat --------

__global__ __launch_bounds__(256)
void prep_kernel(const float* __restrict__ Wq, const float* __restrict__ Wk,
                 const float* __restrict__ Wv, const float* __restrict__ W1,
                 const float* __restrict__ W2,
                 const float* __restrict__ bq, const float* __restrict__ bk,
                 const float* __restrict__ bv, const float* __restrict__ b1,
                 const float* __restrict__ b2,
                 unsigned short* __restrict__ wcat, unsigned short* __restrict__ w1t,
                 unsigned short* __restrict__ w2t, float* __restrict__ bcat) {
    int i = blockIdx.x * 256 + threadIdx.x;
    if (i < 49152) {                       // 3 x 128x128
        int m = i >> 14, j = i & 16383;
        int c = j >> 7, k = j & 127;
        const float* W = (m == 0) ? Wq : (m == 1) ? Wk : Wv;
        wcat[i] = f2bf(W[k * 128 + c]);
    } else if (i < 49152 + 32768) {        // W1: [256 cols x 128 k]
        int j = i - 49152;
        int c = j >> 7, k = j & 127;
        w1t[j] = f2bf(W1[k * 256 + c]);
    } else if (i < 49152 + 65536) {        // W2: [128 cols x 256 k]
        int j = i - 49152 - 32768;
        int c = j >> 8, k = j & 255;
        w2t[j] = f2bf(W2[k * 128 + c]);
    } else if (i < 49152 + 65536 + 768) {
        int j = i - 49152 - 65536;
        float v;
        if (j < 128)      v = bq[j];
        else if (j < 256) v = bk[j - 128];
        else if (j < 384) v = bv[j - 256];
        else if (j < 640) v = b1[j - 384];
        else              v = b2[j - 640];
        bcat[j] = v;
    }
}

// ---- fused QKV GEMM --------------------------------------------------------
// A = x fp32 [N x 128]; blockIdx.y selects Wq/Wk/Wv.
// y=0 -> qb bf16 row-major (= per-head contiguous since D=H*DK).
// y=1 -> kvh k slots; y=2 -> kvh v slots.
// kvh (shorts): node s, head h: k dims at s*256 + h*32 + [0:16),
//                               v dims at s*256 + h*32 + [16:32).

__global__ __launch_bounds__(256)
void qkv_gemm_kernel(const float* __restrict__ A,
                     const unsigned short* __restrict__ wcat,
                     const float* __restrict__ bcat,
                     unsigned short* __restrict__ qb,
                     unsigned short* __restrict__ kvh,
                     int n_rows) {
    __shared__ v8s As[2048];
    __shared__ v8s Bs[2048];

    const int t = threadIdx.x;
    const int l = t & 63;
    const int w = t >> 6;
    const int mhalf = w & 1, nhalf = w >> 1;
    const int rb = blockIdx.x * 128;
    const int y  = blockIdx.y;
    const unsigned short* Bt = wcat + y * 16384;
    const float* bias = bcat + y * 128;

    v4f acc[4][4];
    #pragma unroll
    for (int i = 0; i < 4; ++i)
        #pragma unroll
        for (int j = 0; j < 4; ++j)
            acc[i][j] = (v4f){0.f, 0.f, 0.f, 0.f};

    const int r = t & 127;
    const int tile = r >> 4, m = r & 15;

    #pragma unroll
    for (int it = 0; it < 8; ++it) {
        int k8 = (t >> 7) * 8 + it * 16;
        int chunk = k8 >> 5, j = (k8 >> 3) & 3;
        int dstidx = (tile * 4 + chunk) * 64 + j * 16 + m;
        v8s av = {0, 0, 0, 0, 0, 0, 0, 0};
        if (rb + r < n_rows) {
            const float* ap = &A[(size_t)(rb + r) * 128 + k8];
            float4 f0 = *(const float4*)ap;
            float4 f1 = *(const float4*)(ap + 4);
            av[0] = (short)f2bf(f0.x); av[1] = (short)f2bf(f0.y);
            av[2] = (short)f2bf(f0.z); av[3] = (short)f2bf(f0.w);
            av[4] = (short)f2bf(f1.x); av[5] = (short)f2bf(f1.y);
            av[6] = (short)f2bf(f1.z); av[7] = (short)f2bf(f1.w);
        }
        As[dstidx] = av;
        Bs[dstidx] = *(const v8s*)&Bt[(size_t)r * 128 + k8];
    }
    __syncthreads();

    #pragma unroll
    for (int c = 0; c < 4; ++c) {
        v8s a[4], b[4];
        #pragma unroll
        for (int i = 0; i < 4; ++i)
            a[i] = As[((mhalf * 4 + i) * 4 + c) * 64 + l];
        #pragma unroll
        for (int j = 0; j < 4; ++j)
            b[j] = Bs[((nhalf * 4 + j) * 4 + c) * 64 + l];
        #pragma unroll
        for (int i = 0; i < 4; ++i)
            #pragma unroll
            for (int j = 0; j < 4; ++j)
                acc[i][j] = __builtin_amdgcn_mfma_f32_16x16x32_bf16(a[i], b[j], acc[i][j], 0, 0, 0);
    }

    const int coll = l & 15;
    #pragma unroll
    for (int i = 0; i < 4; ++i) {
        int rtile = rb + (mhalf * 4 + i) * 16 + (l >> 4) * 4;
        #pragma unroll
        for (int j = 0; j < 4; ++j) {
            int c = (nhalf * 4 + j) * 16 + coll;
            float bi = bias[c];
            #pragma unroll
            for (int reg = 0; reg < 4; ++reg) {
                int rr = rtile + reg;
                if (rr >= n_rows) continue;
                unsigned short o = f2bf(acc[i][j][reg] + bi);
                if (y == 0)
                    qb[(size_t)rr * 128 + c] = o;
                else
                    kvh[(size_t)rr * 256 + (c >> 4) * 32 + (c & 15) + (y == 2 ? 16 : 0)] = o;
            }
        }
    }
}

// ---- generic bf16 MFMA GEMM (FFN) ------------------------------------------

__global__ __launch_bounds__(256)
void mfma_gemm_kernel(const unsigned short* __restrict__ A,
                      const unsigned short* __restrict__ Bt,
                      const float* __restrict__ bias,
                      unsigned short* __restrict__ Cb,
                      float* __restrict__ Cf,
                      const float* __restrict__ resid,
                      int n_rows, int K, int ncols, int act) {
    __shared__ v8s As[2048];
    __shared__ v8s Bs[2048];

    const int t = threadIdx.x;
    const int l = t & 63;
    const int w = t >> 6;
    const int mhalf = w & 1, nhalf = w >> 1;
    const int rb = blockIdx.x * 128;
    const int cb = blockIdx.y * 128;

    v4f acc[4][4];
    #pragma unroll
    for (int i = 0; i < 4; ++i)
        #pragma unroll
        for (int j = 0; j < 4; ++j)
            acc[i][j] = (v4f){0.f, 0.f, 0.f, 0.f};

    const int r = t & 127;
    const int tile = r >> 4, m = r & 15;

    for (int kc = 0; kc < K; kc += 128) {
        #pragma unroll
        for (int it = 0; it < 8; ++it) {
            int k8 = (t >> 7) * 8 + it * 16;
            int chunk = k8 >> 5, j = (k8 >> 3) & 3;
            int dstidx = (tile * 4 + chunk) * 64 + j * 16 + m;
            v8s av = {0, 0, 0, 0, 0, 0, 0, 0};
            if (rb + r < n_rows)
                av = *(const v8s*)&A[(size_t)(rb + r) * K + kc + k8];
            As[dstidx] = av;
            Bs[dstidx] = *(const v8s*)&Bt[(size_t)(cb + r) * K + kc + k8];
        }
        __syncthreads();

        #pragma unroll
        for (int c = 0; c < 4; ++c) {
            v8s a[4], b[4];
            #pragma unroll
            for (int i = 0; i < 4; ++i)
                a[i] = As[((mhalf * 4 + i) * 4 + c) * 64 + l];
            #pragma unroll
            for (int j = 0; j < 4; ++j)
                b[j] = Bs[((nhalf * 4 + j) * 4 + c) * 64 + l];
            #pragma unroll
            for (int i = 0; i < 4; ++i)
                #pragma unroll
                for (int j = 0; j < 4; ++j)
                    acc[i][j] = __builtin_amdgcn_mfma_f32_16x16x32_bf16(a[i], b[j], acc[i][j], 0, 0, 0);
        }
        __syncthreads();
    }

    const int coll = l & 15;
    #pragma unroll
    for (int i = 0; i < 4; ++i) {
        int rtile = rb + (mhalf * 4 + i) * 16 + (l >> 4) * 4;
        #pragma unroll
        for (int j = 0; j < 4; ++j) {
            int c = cb + (nhalf * 4 + j) * 16 + coll;
            float bi = bias[c];
            #pragma unroll
            for (int reg = 0; reg < 4; ++reg) {
                int rr = rtile + reg;
                if (rr >= n_rows) continue;
                float vv = acc[i][j][reg] + bi;
                if (act) vv = gelu_exact(vv);
                if (Cf) {
                    float o = vv;
                    if (resid) o += resid[(size_t)rr * ncols + c];
                    Cf[(size_t)rr * ncols + c] = o;
                } else {
                    Cb[(size_t)rr * ncols + c] = f2bf(vv);
                }
            }
        }
    }
}

// ---- Attention + residual + LayerNorm --------------------------------------
// One wave per dst node. lane = slot*8 + head (slot = lane>>3, head = lane&7).
// Each lane processes edge (j + slot) fully in-register for its head:
// k,v = one 64B line from kvh. No online max (scores are O(1): softmax is
// shift-invariant, den >= 1, so plain exp-sums match the reference in fp32).
// Per-slot partial (l, acc[16]) merged across slots by shfl_xor(8/16/32).

__global__ __launch_bounds__(256)
void attn_ln_kernel(const unsigned short* __restrict__ q,
                    const unsigned short* __restrict__ kvh,
                    const float* __restrict__ x,
                    const int* __restrict__ offs, const int* __restrict__ esrc,
                    const float* __restrict__ ln_g, const float* __restrict__ ln_b,
                    float* __restrict__ hb, unsigned short* __restrict__ hnb, int n) {
    const int wave = threadIdx.x >> 6;
    const int lane = threadIdx.x & 63;
    const int node = blockIdx.x * 4 + wave;
    if (node >= n) return;
    const int head = lane & 7;
    const int slot = lane >> 3;

    // q fragment for this head (16 dims)
    const unsigned int* qp = (const unsigned int*)&q[(size_t)node * 128 + head * 16];
    float2 qv[8];
    #pragma unroll
    for (int i = 0; i < 8; ++i) qv[i] = bf2_to_f2(qp[i]);

    const int e0 = offs[node], e1 = offs[node + 1];

    float l = 0.f;
    float2 acc[8];
    #pragma unroll
    for (int i = 0; i < 8; ++i) acc[i] = make_float2(0.f, 0.f);

    if (e1 > e0) {
        for (int j = e0; j < e1; j += 8) {
            int eidx = j + slot;
            bool valid = eidx < e1;
            int s = esrc[valid ? eidx : e1 - 1];
            const uint4* kp = (const uint4*)&kvh[(size_t)s * 256 + head * 32];
            uint4 ka = kp[0], kb = kp[1], va = kp[2], vb = kp[3];

            float2 f;
            float dot = 0.f;
            f = bf2_to_f2(ka.x); dot = fmaf(f.x, qv[0].x, fmaf(f.y, qv[0].y, dot));
            f = bf2_to_f2(ka.y); dot = fmaf(f.x, qv[1].x, fmaf(f.y, qv[1].y, dot));
            f = bf2_to_f2(ka.z); dot = fmaf(f.x, qv[2].x, fmaf(f.y, qv[2].y, dot));
            f = bf2_to_f2(ka.w); dot = fmaf(f.x, qv[3].x, fmaf(f.y, qv[3].y, dot));
            f = bf2_to_f2(kb.x); dot = fmaf(f.x, qv[4].x, fmaf(f.y, qv[4].y, dot));
            f = bf2_to_f2(kb.y); dot = fmaf(f.x, qv[5].x, fmaf(f.y, qv[5].y, dot));
            f = bf2_to_f2(kb.z); dot = fmaf(f.x, qv[6].x, fmaf(f.y, qv[6].y, dot));
            f = bf2_to_f2(kb.w); dot = fmaf(f.x, qv[7].x, fmaf(f.y, qv[7].y, dot));

            float pe = valid ? __expf(dot * 0.25f) : 0.f;
            l += pe;

            f = bf2_to_f2(va.x); acc[0].x = fmaf(pe, f.x, acc[0].x); acc[0].y = fmaf(pe, f.y, acc[0].y);
            f = bf2_to_f2(va.y); acc[1].x = fmaf(pe, f.x, acc[1].x); acc[1].y = fmaf(pe, f.y, acc[1].y);
            f = bf2_to_f2(va.z); acc[2].x = fmaf(pe, f.x, acc[2].x); acc[2].y = fmaf(pe, f.y, acc[2].y);
            f = bf2_to_f2(va.w); acc[3].x = fmaf(pe, f.x, acc[3].x); acc[3].y = fmaf(pe, f.y, acc[3].y);
            f = bf2_to_f2(vb.x); acc[4].x = fmaf(pe, f.x, acc[4].x); acc[4].y = fmaf(pe, f.y, acc[4].y);
            f = bf2_to_f2(vb.y); acc[5].x = fmaf(pe, f.x, acc[5].x); acc[5].y = fmaf(pe, f.y, acc[5].y);
            f = bf2_to_f2(vb.z); acc[6].x = fmaf(pe, f.x, acc[6].x); acc[6].y = fmaf(pe, f.y, acc[6].y);
            f = bf2_to_f2(vb.w); acc[7].x = fmaf(pe, f.x, acc[7].x); acc[7].y = fmaf(pe, f.y, acc[7].y);
        }
    }

    // merge partial sums across the 8 slots
    #pragma unroll
    for (int off = 8; off <= 32; off <<= 1) {
        l += __shfl_xor(l, off, 64);
        #pragma unroll
        for (int i = 0; i < 8; ++i) {
            acc[i].x += __shfl_xor(acc[i].x, off, 64);
            acc[i].y += __shfl_xor(acc[i].y, off, 64);
        }
    }

    float inv = 1.f / (l + 1e-16f);

    // lane writes dims d = head*16 + slot*2 + {0,1}
    const int d = head * 16 + slot * 2;
    float2 o = acc[slot];
    float2 xv = *(const float2*)&x[(size_t)node * 128 + d];
    float2 hv = make_float2(o.x * inv + xv.x, o.y * inv + xv.y);
    *(float2*)&hb[(size_t)node * 128 + d] = hv;

    // fused LayerNorm over the wave (full row present: 64 lanes x 2 dims)
    float s  = hv.x + hv.y;
    float s2 = hv.x * hv.x + hv.y * hv.y;
    #pragma unroll
    for (int off = 1; off < 64; off <<= 1) {
        s  += __shfl_xor(s, off, 64);
        s2 += __shfl_xor(s2, off, 64);
    }
    float mu  = s * (1.f / 128.f);
    float var = s2 * (1.f / 128.f) - mu * mu;
    float rstd = rsqrtf(var + 1e-5f);
    float2 gv = *(const float2*)&ln_g[d];
    float2 bv = *(const float2*)&ln_b[d];
    ushort2 ob;
    ob.x = f2bf((hv.x - mu) * rstd * gv.x + bv.x);
    ob.y = f2bf((hv.y - mu) * rstd * gv.y + bv.y);
    *(ushort2*)&hnb[(size_t)node * 128 + d] = ob;
}

// ---------------------------------------------------------------------------

extern "C" void kernel_launch(void* const* d_in, const int* in_sizes, int n_in,
                              void* d_out, int out_size, void* d_ws, size_t ws_size,
                              hipStream_t stream) {
    const float* x    = (const float*)d_in[0];
    const int*   ei   = (const int*)d_in[1];
    const float* Wq   = (const float*)d_in[2];
    const float* bq   = (const float*)d_in[3];
    const float* Wk   = (const float*)d_in[4];
    const float* bk   = (const float*)d_in[5];
    const float* Wv   = (const float*)d_in[6];
    const float* bv   = (const float*)d_in[7];
    const float* ln_g = (const float*)d_in[8];
    const float* ln_b = (const float*)d_in[9];
    const float* W1   = (const float*)d_in[10];
    const float* b1   = (const float*)d_in[11];
    const float* W2   = (const float*)d_in[12];
    const float* b2   = (const float*)d_in[13];
    float* out = (float*)d_out;

    const int D = 128;
    const int N = in_sizes[0] / D;
    const int E = in_sizes[1] / 2;
    const int* src = ei;
    const int* dst = ei + E;

    const size_t ND = (size_t)N * D;
    unsigned short* qb  = (unsigned short*)d_ws;        // N*128 bf16
    unsigned short* kvh = qb + ND;                      // N*256 bf16 (k/v per head)
    float*          hb  = (float*)(kvh + 2 * ND);       // N*128 fp32
    unsigned short* hnb = (unsigned short*)(hb + ND);   // N*128 bf16
    unsigned short* wcat = hnb + ND;                    // 3*16384
    unsigned short* w1t  = wcat + 49152;                // 32768
    unsigned short* w2t  = w1t + 32768;                 // 32768
    float* bcat = (float*)(w2t + 32768);                // 768 floats
    int* cnt  = (int*)(bcat + 768);
    int* offs = cnt + N;
    int* bsum = offs + N + 1;                           // up to 256
    int* esrc = bsum + 256;                             // E ints
    unsigned short* hid = qb;                           // alias: N*256 bf16 over q+kvh

    // CSR build: one cooperative kernel (zero+hist+scan+scatter)
    {
        int nN = N, nE = E;
        void* args[] = { (void*)&src, (void*)&dst, (void*)&cnt, (void*)&offs,
                         (void*)&bsum, (void*)&esrc, (void*)&nN, (void*)&nE };
        hipLaunchCooperativeKernel((const void*)csr_kernel, dim3(512), dim3(256),
                                   args, 0, stream);
    }

    // weights prep
    prep_kernel<<<(49152 + 65536 + 768 + 255) / 256, 256, 0, stream>>>(
        Wq, Wk, Wv, W1, W2, bq, bk, bv, b1, b2, wcat, w1t, w2t, bcat);

    // fused QKV projection
    const int rt = (N + 127) / 128;
    qkv_gemm_kernel<<<dim3(rt, 3), 256, 0, stream>>>(x, wcat, bcat, qb, kvh, N);

    // attention + residual + LN
    attn_ln_kernel<<<(N + 3) / 4, 256, 0, stream>>>(qb, kvh, x, offs, esrc,
                                                    ln_g, ln_b, hb, hnb, N);

    // FFN
    mfma_gemm_kernel<<<dim3(rt, 2), 256, 0, stream>>>(hnb, w1t, bcat + 384, hid,
                                                      nullptr, nullptr, N, 128, 256, 1);
    mfma_gemm_kernel<<<dim3(rt, 1), 256, 0, stream>>>(hid, w2t, bcat + 640, nullptr,
                                                      out, hb, N, 256, 128, 0);
}

// Round 5
// 387.371 us; speedup vs baseline: 1.7466x; 1.7466x over previous
//
#include <hip/hip_runtime.h>
#include <cmath>

// ---------------------------------------------------------------------------
// StructuralAttentionLayer on MI355X (gfx950)
// N=50000, E=800000, D=128, H=8, DK=16
// Round 4: round-3 attention (slot*head layout) + round-2 CSR build
// (separate dispatches — cooperative grid.sync measured at ~55us/sync, DO NOT
// use it here).
// ---------------------------------------------------------------------------

typedef short v8s __attribute__((ext_vector_type(8)));   // 8 bf16 (4 VGPRs)
typedef float v4f __attribute__((ext_vector_type(4)));   // 4 fp32 acc

__device__ __forceinline__ float gelu_exact(float x) {
    return 0.5f * x * (1.0f + erff(x * 0.70710678118654752440f));
}

__device__ __forceinline__ unsigned short f2bf(float f) {
    unsigned int u = __float_as_uint(f);
    u = (u + 0x7fffu + ((u >> 16) & 1u)) >> 16;
    return (unsigned short)u;
}

__device__ __forceinline__ float2 bf2_to_f2(unsigned int u) {
    float2 r;
    r.x = __uint_as_float(u << 16);
    r.y = __uint_as_float(u & 0xffff0000u);
    return r;
}

// ---- CSR build (separate dispatches) ---------------------------------------

__global__ __launch_bounds__(256)
void hist_kernel(const int* __restrict__ dst, int* __restrict__ cnt, int E) {
    int e = blockIdx.x * 256 + threadIdx.x;
    if (e < E) atomicAdd(&cnt[dst[e]], 1);
}

__global__ __launch_bounds__(256)
void scan_blk_kernel(const int* __restrict__ cnt, int* __restrict__ offs,
                     int* __restrict__ bsum, int n) {
    __shared__ int ws[4];
    const int t = threadIdx.x, wid = t >> 6, lane = t & 63;
    int i = blockIdx.x * 256 + t;
    int v = (i < n) ? cnt[i] : 0;
    int incl = v;
    #pragma unroll
    for (int off = 1; off < 64; off <<= 1) {
        int u = __shfl_up(incl, off, 64);
        if (lane >= off) incl += u;
    }
    if (lane == 63) ws[wid] = incl;
    __syncthreads();
    int prefix = 0, tot = 0;
    #pragma unroll
    for (int w = 0; w < 4; ++w) {
        int s = ws[w];
        if (w < wid) prefix += s;
        tot += s;
    }
    if (i < n) offs[i] = prefix + incl - v;
    if (t == 0) bsum[blockIdx.x] = tot;
}

__global__ __launch_bounds__(256)
void scan_top_kernel(int* __restrict__ bsum, int nb) {
    __shared__ int ws[4];
    const int t = threadIdx.x, wid = t >> 6, lane = t & 63;
    int v = (t < nb) ? bsum[t] : 0;
    int incl = v;
    #pragma unroll
    for (int off = 1; off < 64; off <<= 1) {
        int u = __shfl_up(incl, off, 64);
        if (lane >= off) incl += u;
    }
    if (lane == 63) ws[wid] = incl;
    __syncthreads();
    int prefix = 0;
    #pragma unroll
    for (int w = 0; w < 4; ++w)
        if (w < wid) prefix += ws[w];
    if (t < nb) bsum[t] = prefix + incl - v;
}

__global__ __launch_bounds__(256)
void scan_add_kernel(int* __restrict__ offs, const int* __restrict__ bsum,
                     int* __restrict__ cursor, int n, int E) {
    int i = blockIdx.x * 256 + threadIdx.x;
    if (i < n) {
        int o = offs[i] + bsum[blockIdx.x];
        offs[i] = o;
        cursor[i] = o;
    }
    if (i == n) offs[n] = E;
}

__global__ __launch_bounds__(256)
void scatter_kernel(const int* __restrict__ src, const int* __restrict__ dst,
                    int* __restrict__ cursor, int* __restrict__ esrc, int E) {
    int e = blockIdx.x * 256 + threadIdx.x;
    if (e < E) {
        int p = atomicAdd(&cursor[dst[e]], 1);
        esrc[p] = src[e];
    }
}

// ---- prep: weight transposes (fp32 -> bf16, [col][k]) + bias concat --------

__global__ __launch_bounds__(256)
void prep_kernel(const float* __restrict__ Wq, const float* __restrict__ Wk,
                 const float* __restrict__ Wv, const float* __restrict__ W1,
                 const float* __restrict__ W2,
                 const float* __restrict__ bq, const float* __restrict__ bk,
                 const float* __restrict__ bv, const float* __restrict__ b1,
                 const float* __restrict__ b2,
                 unsigned short* __restrict__ wcat, unsigned short* __restrict__ w1t,
                 unsigned short* __restrict__ w2t, float* __restrict__ bcat) {
    int i = blockIdx.x * 256 + threadIdx.x;
    if (i < 49152) {                       // 3 x 128x128
        int m = i >> 14, j = i & 16383;
        int c = j >> 7, k = j & 127;
        const float* W = (m == 0) ? Wq : (m == 1) ? Wk : Wv;
        wcat[i] = f2bf(W[k * 128 + c]);
    } else if (i < 49152 + 32768) {        // W1: [256 cols x 128 k]
        int j = i - 49152;
        int c = j >> 7, k = j & 127;
        w1t[j] = f2bf(W1[k * 256 + c]);
    } else if (i < 49152 + 65536) {        // W2: [128 cols x 256 k]
        int j = i - 49152 - 32768;
        int c = j >> 8, k = j & 255;
        w2t[j] = f2bf(W2[k * 128 + c]);
    } else if (i < 49152 + 65536 + 768) {
        int j = i - 49152 - 65536;
        float v;
        if (j < 128)      v = bq[j];
        else if (j < 256) v = bk[j - 128];
        else if (j < 384) v = bv[j - 256];
        else if (j < 640) v = b1[j - 384];
        else              v = b2[j - 640];
        bcat[j] = v;
    }
}

// ---- fused QKV GEMM --------------------------------------------------------
// A = x fp32 [N x 128]; blockIdx.y selects Wq/Wk/Wv.
// y=0 -> qb bf16 row-major; y=1 -> kvh k slots; y=2 -> kvh v slots.
// kvh (shorts): node s, head h: k at s*256 + h*32 + [0:16), v at +16.

__global__ __launch_bounds__(256)
void qkv_gemm_kernel(const float* __restrict__ A,
                     const unsigned short* __restrict__ wcat,
                     const float* __restrict__ bcat,
                     unsigned short* __restrict__ qb,
                     unsigned short* __restrict__ kvh,
                     int n_rows) {
    __shared__ v8s As[2048];
    __shared__ v8s Bs[2048];

    const int t = threadIdx.x;
    const int l = t & 63;
    const int w = t >> 6;
    const int mhalf = w & 1, nhalf = w >> 1;
    const int rb = blockIdx.x * 128;
    const int y  = blockIdx.y;
    const unsigned short* Bt = wcat + y * 16384;
    const float* bias = bcat + y * 128;

    v4f acc[4][4];
    #pragma unroll
    for (int i = 0; i < 4; ++i)
        #pragma unroll
        for (int j = 0; j < 4; ++j)
            acc[i][j] = (v4f){0.f, 0.f, 0.f, 0.f};

    const int r = t & 127;
    const int tile = r >> 4, m = r & 15;

    #pragma unroll
    for (int it = 0; it < 8; ++it) {
        int k8 = (t >> 7) * 8 + it * 16;
        int chunk = k8 >> 5, j = (k8 >> 3) & 3;
        int dstidx = (tile * 4 + chunk) * 64 + j * 16 + m;
        v8s av = {0, 0, 0, 0, 0, 0, 0, 0};
        if (rb + r < n_rows) {
            const float* ap = &A[(size_t)(rb + r) * 128 + k8];
            float4 f0 = *(const float4*)ap;
            float4 f1 = *(const float4*)(ap + 4);
            av[0] = (short)f2bf(f0.x); av[1] = (short)f2bf(f0.y);
            av[2] = (short)f2bf(f0.z); av[3] = (short)f2bf(f0.w);
            av[4] = (short)f2bf(f1.x); av[5] = (short)f2bf(f1.y);
            av[6] = (short)f2bf(f1.z); av[7] = (short)f2bf(f1.w);
        }
        As[dstidx] = av;
        Bs[dstidx] = *(const v8s*)&Bt[(size_t)r * 128 + k8];
    }
    __syncthreads();

    #pragma unroll
    for (int c = 0; c < 4; ++c) {
        v8s a[4], b[4];
        #pragma unroll
        for (int i = 0; i < 4; ++i)
            a[i] = As[((mhalf * 4 + i) * 4 + c) * 64 + l];
        #pragma unroll
        for (int j = 0; j < 4; ++j)
            b[j] = Bs[((nhalf * 4 + j) * 4 + c) * 64 + l];
        #pragma unroll
        for (int i = 0; i < 4; ++i)
            #pragma unroll
            for (int j = 0; j < 4; ++j)
                acc[i][j] = __builtin_amdgcn_mfma_f32_16x16x32_bf16(a[i], b[j], acc[i][j], 0, 0, 0);
    }

    const int coll = l & 15;
    #pragma unroll
    for (int i = 0; i < 4; ++i) {
        int rtile = rb + (mhalf * 4 + i) * 16 + (l >> 4) * 4;
        #pragma unroll
        for (int j = 0; j < 4; ++j) {
            int c = (nhalf * 4 + j) * 16 + coll;
            float bi = bias[c];
            #pragma unroll
            for (int reg = 0; reg < 4; ++reg) {
                int rr = rtile + reg;
                if (rr >= n_rows) continue;
                unsigned short o = f2bf(acc[i][j][reg] + bi);
                if (y == 0)
                    qb[(size_t)rr * 128 + c] = o;
                else
                    kvh[(size_t)rr * 256 + (c >> 4) * 32 + (c & 15) + (y == 2 ? 16 : 0)] = o;
            }
        }
    }
}

// ---- generic bf16 MFMA GEMM (FFN) ------------------------------------------

__global__ __launch_bounds__(256)
void mfma_gemm_kernel(const unsigned short* __restrict__ A,
                      const unsigned short* __restrict__ Bt,
                      const float* __restrict__ bias,
                      unsigned short* __restrict__ Cb,
                      float* __restrict__ Cf,
                      const float* __restrict__ resid,
                      int n_rows, int K, int ncols, int act) {
    __shared__ v8s As[2048];
    __shared__ v8s Bs[2048];

    const int t = threadIdx.x;
    const int l = t & 63;
    const int w = t >> 6;
    const int mhalf = w & 1, nhalf = w >> 1;
    const int rb = blockIdx.x * 128;
    const int cb = blockIdx.y * 128;

    v4f acc[4][4];
    #pragma unroll
    for (int i = 0; i < 4; ++i)
        #pragma unroll
        for (int j = 0; j < 4; ++j)
            acc[i][j] = (v4f){0.f, 0.f, 0.f, 0.f};

    const int r = t & 127;
    const int tile = r >> 4, m = r & 15;

    for (int kc = 0; kc < K; kc += 128) {
        #pragma unroll
        for (int it = 0; it < 8; ++it) {
            int k8 = (t >> 7) * 8 + it * 16;
            int chunk = k8 >> 5, j = (k8 >> 3) & 3;
            int dstidx = (tile * 4 + chunk) * 64 + j * 16 + m;
            v8s av = {0, 0, 0, 0, 0, 0, 0, 0};
            if (rb + r < n_rows)
                av = *(const v8s*)&A[(size_t)(rb + r) * K + kc + k8];
            As[dstidx] = av;
            Bs[dstidx] = *(const v8s*)&Bt[(size_t)(cb + r) * K + kc + k8];
        }
        __syncthreads();

        #pragma unroll
        for (int c = 0; c < 4; ++c) {
            v8s a[4], b[4];
            #pragma unroll
            for (int i = 0; i < 4; ++i)
                a[i] = As[((mhalf * 4 + i) * 4 + c) * 64 + l];
            #pragma unroll
            for (int j = 0; j < 4; ++j)
                b[j] = Bs[((nhalf * 4 + j) * 4 + c) * 64 + l];
            #pragma unroll
            for (int i = 0; i < 4; ++i)
                #pragma unroll
                for (int j = 0; j < 4; ++j)
                    acc[i][j] = __builtin_amdgcn_mfma_f32_16x16x32_bf16(a[i], b[j], acc[i][j], 0, 0, 0);
        }
        __syncthreads();
    }

    const int coll = l & 15;
    #pragma unroll
    for (int i = 0; i < 4; ++i) {
        int rtile = rb + (mhalf * 4 + i) * 16 + (l >> 4) * 4;
        #pragma unroll
        for (int j = 0; j < 4; ++j) {
            int c = cb + (nhalf * 4 + j) * 16 + coll;
            float bi = bias[c];
            #pragma unroll
            for (int reg = 0; reg < 4; ++reg) {
                int rr = rtile + reg;
                if (rr >= n_rows) continue;
                float vv = acc[i][j][reg] + bi;
                if (act) vv = gelu_exact(vv);
                if (Cf) {
                    float o = vv;
                    if (resid) o += resid[(size_t)rr * ncols + c];
                    Cf[(size_t)rr * ncols + c] = o;
                } else {
                    Cb[(size_t)rr * ncols + c] = f2bf(vv);
                }
            }
        }
    }
}

// ---- Attention + residual + LayerNorm --------------------------------------
// One wave per dst node. lane = slot*8 + head (slot = lane>>3, head = lane&7).
// Each lane processes edge (j + slot) fully in-register for its head:
// k,v = one 64B line from kvh. No online max (scores are O(1): softmax is
// shift-invariant, den >= 1, so plain exp-sums match the reference in fp32).
// Per-slot partial (l, acc[16]) merged across slots by shfl_xor(8/16/32).

__global__ __launch_bounds__(256)
void attn_ln_kernel(const unsigned short* __restrict__ q,
                    const unsigned short* __restrict__ kvh,
                    const float* __restrict__ x,
                    const int* __restrict__ offs, const int* __restrict__ esrc,
                    const float* __restrict__ ln_g, const float* __restrict__ ln_b,
                    float* __restrict__ hb, unsigned short* __restrict__ hnb, int n) {
    const int wave = threadIdx.x >> 6;
    const int lane = threadIdx.x & 63;
    const int node = blockIdx.x * 4 + wave;
    if (node >= n) return;
    const int head = lane & 7;
    const int slot = lane >> 3;

    const unsigned int* qp = (const unsigned int*)&q[(size_t)node * 128 + head * 16];
    float2 qv[8];
    #pragma unroll
    for (int i = 0; i < 8; ++i) qv[i] = bf2_to_f2(qp[i]);

    const int e0 = offs[node], e1 = offs[node + 1];

    float l = 0.f;
    float2 acc[8];
    #pragma unroll
    for (int i = 0; i < 8; ++i) acc[i] = make_float2(0.f, 0.f);

    if (e1 > e0) {
        for (int j = e0; j < e1; j += 8) {
            int eidx = j + slot;
            bool valid = eidx < e1;
            int s = esrc[valid ? eidx : e1 - 1];
            const uint4* kp = (const uint4*)&kvh[(size_t)s * 256 + head * 32];
            uint4 ka = kp[0], kb = kp[1], va = kp[2], vb = kp[3];

            float2 f;
            float dot = 0.f;
            f = bf2_to_f2(ka.x); dot = fmaf(f.x, qv[0].x, fmaf(f.y, qv[0].y, dot));
            f = bf2_to_f2(ka.y); dot = fmaf(f.x, qv[1].x, fmaf(f.y, qv[1].y, dot));
            f = bf2_to_f2(ka.z); dot = fmaf(f.x, qv[2].x, fmaf(f.y, qv[2].y, dot));
            f = bf2_to_f2(ka.w); dot = fmaf(f.x, qv[3].x, fmaf(f.y, qv[3].y, dot));
            f = bf2_to_f2(kb.x); dot = fmaf(f.x, qv[4].x, fmaf(f.y, qv[4].y, dot));
            f = bf2_to_f2(kb.y); dot = fmaf(f.x, qv[5].x, fmaf(f.y, qv[5].y, dot));
            f = bf2_to_f2(kb.z); dot = fmaf(f.x, qv[6].x, fmaf(f.y, qv[6].y, dot));
            f = bf2_to_f2(kb.w); dot = fmaf(f.x, qv[7].x, fmaf(f.y, qv[7].y, dot));

            float pe = valid ? __expf(dot * 0.25f) : 0.f;
            l += pe;

            f = bf2_to_f2(va.x); acc[0].x = fmaf(pe, f.x, acc[0].x); acc[0].y = fmaf(pe, f.y, acc[0].y);
            f = bf2_to_f2(va.y); acc[1].x = fmaf(pe, f.x, acc[1].x); acc[1].y = fmaf(pe, f.y, acc[1].y);
            f = bf2_to_f2(va.z); acc[2].x = fmaf(pe, f.x, acc[2].x); acc[2].y = fmaf(pe, f.y, acc[2].y);
            f = bf2_to_f2(va.w); acc[3].x = fmaf(pe, f.x, acc[3].x); acc[3].y = fmaf(pe, f.y, acc[3].y);
            f = bf2_to_f2(vb.x); acc[4].x = fmaf(pe, f.x, acc[4].x); acc[4].y = fmaf(pe, f.y, acc[4].y);
            f = bf2_to_f2(vb.y); acc[5].x = fmaf(pe, f.x, acc[5].x); acc[5].y = fmaf(pe, f.y, acc[5].y);
            f = bf2_to_f2(vb.z); acc[6].x = fmaf(pe, f.x, acc[6].x); acc[6].y = fmaf(pe, f.y, acc[6].y);
            f = bf2_to_f2(vb.w); acc[7].x = fmaf(pe, f.x, acc[7].x); acc[7].y = fmaf(pe, f.y, acc[7].y);
        }
    }

    #pragma unroll
    for (int off = 8; off <= 32; off <<= 1) {
        l += __shfl_xor(l, off, 64);
        #pragma unroll
        for (int i = 0; i < 8; ++i) {
            acc[i].x += __shfl_xor(acc[i].x, off, 64);
            acc[i].y += __shfl_xor(acc[i].y, off, 64);
        }
    }

    float inv = 1.f / (l + 1e-16f);

    const int d = head * 16 + slot * 2;
    float2 o = acc[slot];
    float2 xv = *(const float2*)&x[(size_t)node * 128 + d];
    float2 hv = make_float2(o.x * inv + xv.x, o.y * inv + xv.y);
    *(float2*)&hb[(size_t)node * 128 + d] = hv;

    float s  = hv.x + hv.y;
    float s2 = hv.x * hv.x + hv.y * hv.y;
    #pragma unroll
    for (int off = 1; off < 64; off <<= 1) {
        s  += __shfl_xor(s, off, 64);
        s2 += __shfl_xor(s2, off, 64);
    }
    float mu  = s * (1.f / 128.f);
    float var = s2 * (1.f / 128.f) - mu * mu;
    float rstd = rsqrtf(var + 1e-5f);
    float2 gv = *(const float2*)&ln_g[d];
    float2 bv = *(const float2*)&ln_b[d];
    ushort2 ob;
    ob.x = f2bf((hv.x - mu) * rstd * gv.x + bv.x);
    ob.y = f2bf((hv.y - mu) * rstd * gv.y + bv.y);
    *(ushort2*)&hnb[(size_t)node * 128 + d] = ob;
}

// ---------------------------------------------------------------------------

extern "C" void kernel_launch(void* const* d_in, const int* in_sizes, int n_in,
                              void* d_out, int out_size, void* d_ws, size_t ws_size,
                              hipStream_t stream) {
    const float* x    = (const float*)d_in[0];
    const int*   ei   = (const int*)d_in[1];
    const float* Wq   = (const float*)d_in[2];
    const float* bq   = (const float*)d_in[3];
    const float* Wk   = (const float*)d_in[4];
    const float* bk   = (const float*)d_in[5];
    const float* Wv   = (const float*)d_in[6];
    const float* bv   = (const float*)d_in[7];
    const float* ln_g = (const float*)d_in[8];
    const float* ln_b = (const float*)d_in[9];
    const float* W1   = (const float*)d_in[10];
    const float* b1   = (const float*)d_in[11];
    const float* W2   = (const float*)d_in[12];
    const float* b2   = (const float*)d_in[13];
    float* out = (float*)d_out;

    const int D = 128;
    const int N = in_sizes[0] / D;
    const int E = in_sizes[1] / 2;
    const int* src = ei;
    const int* dst = ei + E;

    const size_t ND = (size_t)N * D;
    unsigned short* qb  = (unsigned short*)d_ws;        // N*128 bf16
    unsigned short* kvh = qb + ND;                      // N*256 bf16 (k/v per head)
    float*          hb  = (float*)(kvh + 2 * ND);       // N*128 fp32
    unsigned short* hnb = (unsigned short*)(hb + ND);   // N*128 bf16
    unsigned short* wcat = hnb + ND;                    // 3*16384
    unsigned short* w1t  = wcat + 49152;                // 32768
    unsigned short* w2t  = w1t + 32768;                 // 32768
    float* bcat = (float*)(w2t + 32768);                // 768 floats
    int* cnt  = (int*)(bcat + 768);
    int* offs = cnt + N;
    int* bsum = offs + N + 1;                           // up to 256
    int* esrc = bsum + 256;                             // E ints
    unsigned short* hid = qb;                           // alias: N*256 bf16 over q+kvh

    const int nblk = (N + 255) / 256;   // 196

    // CSR build (by dst) — separate dispatches
    hipMemsetAsync(cnt, 0, sizeof(int) * N, stream);
    hist_kernel<<<(E + 255) / 256, 256, 0, stream>>>(dst, cnt, E);
    scan_blk_kernel<<<nblk, 256, 0, stream>>>(cnt, offs, bsum, N);
    scan_top_kernel<<<1, 256, 0, stream>>>(bsum, nblk);
    scan_add_kernel<<<nblk, 256, 0, stream>>>(offs, bsum, cnt, N, E);
    scatter_kernel<<<(E + 255) / 256, 256, 0, stream>>>(src, dst, cnt, esrc, E);

    // weights prep
    prep_kernel<<<(49152 + 65536 + 768 + 255) / 256, 256, 0, stream>>>(
        Wq, Wk, Wv, W1, W2, bq, bk, bv, b1, b2, wcat, w1t, w2t, bcat);

    // fused QKV projection
    const int rt = (N + 127) / 128;
    qkv_gemm_kernel<<<dim3(rt, 3), 256, 0, stream>>>(x, wcat, bcat, qb, kvh, N);

    // attention + residual + LN
    attn_ln_kernel<<<(N + 3) / 4, 256, 0, stream>>>(qb, kvh, x, offs, esrc,
                                                    ln_g, ln_b, hb, hnb, N);

    // FFN
    mfma_gemm_kernel<<<dim3(rt, 2), 256, 0, stream>>>(hnb, w1t, bcat + 384, hid,
                                                      nullptr, nullptr, N, 128, 256, 1);
    mfma_gemm_kernel<<<dim3(rt, 1), 256, 0, stream>>>(hid, w2t, bcat + 640, nullptr,
                                                      out, hb, N, 256, 128, 0);
}

// Round 6
// 368.810 us; speedup vs baseline: 1.8345x; 1.0503x over previous
//
#include <hip/hip_runtime.h>
#include <cmath>

// ---------------------------------------------------------------------------
// StructuralAttentionLayer on MI355X (gfx950)
// N=50000, E=800000, D=128, H=8, DK=16
// Round 5: fix R4's attn regression — `acc[slot]` dynamic register-array index
// made the compiler spill acc[] to LDS (LDS_Block_Size=16384, 7.9M bank
// conflicts). Replaced with a reduce-scatter butterfly (14 shuffles, no
// dynamic indexing). CSR stays as separate dispatches (cooperative grid.sync
// measured ~55us/sync on this chip — do not use).
// ---------------------------------------------------------------------------

typedef short v8s __attribute__((ext_vector_type(8)));   // 8 bf16 (4 VGPRs)
typedef float v4f __attribute__((ext_vector_type(4)));   // 4 fp32 acc

__device__ __forceinline__ float gelu_exact(float x) {
    return 0.5f * x * (1.0f + erff(x * 0.70710678118654752440f));
}

__device__ __forceinline__ unsigned short f2bf(float f) {
    unsigned int u = __float_as_uint(f);
    u = (u + 0x7fffu + ((u >> 16) & 1u)) >> 16;
    return (unsigned short)u;
}

__device__ __forceinline__ float2 bf2_to_f2(unsigned int u) {
    float2 r;
    r.x = __uint_as_float(u << 16);
    r.y = __uint_as_float(u & 0xffff0000u);
    return r;
}

// ---- CSR build (separate dispatches) ---------------------------------------

__global__ __launch_bounds__(256)
void hist_kernel(const int* __restrict__ dst, int* __restrict__ cnt, int E) {
    int e = blockIdx.x * 256 + threadIdx.x;
    if (e < E) atomicAdd(&cnt[dst[e]], 1);
}

__global__ __launch_bounds__(256)
void scan_blk_kernel(const int* __restrict__ cnt, int* __restrict__ offs,
                     int* __restrict__ bsum, int n) {
    __shared__ int ws[4];
    const int t = threadIdx.x, wid = t >> 6, lane = t & 63;
    int i = blockIdx.x * 256 + t;
    int v = (i < n) ? cnt[i] : 0;
    int incl = v;
    #pragma unroll
    for (int off = 1; off < 64; off <<= 1) {
        int u = __shfl_up(incl, off, 64);
        if (lane >= off) incl += u;
    }
    if (lane == 63) ws[wid] = incl;
    __syncthreads();
    int prefix = 0, tot = 0;
    #pragma unroll
    for (int w = 0; w < 4; ++w) {
        int s = ws[w];
        if (w < wid) prefix += s;
        tot += s;
    }
    if (i < n) offs[i] = prefix + incl - v;
    if (t == 0) bsum[blockIdx.x] = tot;
}

__global__ __launch_bounds__(256)
void scan_top_kernel(int* __restrict__ bsum, int nb) {
    __shared__ int ws[4];
    const int t = threadIdx.x, wid = t >> 6, lane = t & 63;
    int v = (t < nb) ? bsum[t] : 0;
    int incl = v;
    #pragma unroll
    for (int off = 1; off < 64; off <<= 1) {
        int u = __shfl_up(incl, off, 64);
        if (lane >= off) incl += u;
    }
    if (lane == 63) ws[wid] = incl;
    __syncthreads();
    int prefix = 0;
    #pragma unroll
    for (int w = 0; w < 4; ++w)
        if (w < wid) prefix += ws[w];
    if (t < nb) bsum[t] = prefix + incl - v;
}

__global__ __launch_bounds__(256)
void scan_add_kernel(int* __restrict__ offs, const int* __restrict__ bsum,
                     int* __restrict__ cursor, int n, int E) {
    int i = blockIdx.x * 256 + threadIdx.x;
    if (i < n) {
        int o = offs[i] + bsum[blockIdx.x];
        offs[i] = o;
        cursor[i] = o;
    }
    if (i == n) offs[n] = E;
}

__global__ __launch_bounds__(256)
void scatter_kernel(const int* __restrict__ src, const int* __restrict__ dst,
                    int* __restrict__ cursor, int* __restrict__ esrc, int E) {
    int e = blockIdx.x * 256 + threadIdx.x;
    if (e < E) {
        int p = atomicAdd(&cursor[dst[e]], 1);
        esrc[p] = src[e];
    }
}

// ---- prep: weight transposes (fp32 -> bf16, [col][k]) + bias concat --------

__global__ __launch_bounds__(256)
void prep_kernel(const float* __restrict__ Wq, const float* __restrict__ Wk,
                 const float* __restrict__ Wv, const float* __restrict__ W1,
                 const float* __restrict__ W2,
                 const float* __restrict__ bq, const float* __restrict__ bk,
                 const float* __restrict__ bv, const float* __restrict__ b1,
                 const float* __restrict__ b2,
                 unsigned short* __restrict__ wcat, unsigned short* __restrict__ w1t,
                 unsigned short* __restrict__ w2t, float* __restrict__ bcat) {
    int i = blockIdx.x * 256 + threadIdx.x;
    if (i < 49152) {                       // 3 x 128x128
        int m = i >> 14, j = i & 16383;
        int c = j >> 7, k = j & 127;
        const float* W = (m == 0) ? Wq : (m == 1) ? Wk : Wv;
        wcat[i] = f2bf(W[k * 128 + c]);
    } else if (i < 49152 + 32768) {        // W1: [256 cols x 128 k]
        int j = i - 49152;
        int c = j >> 7, k = j & 127;
        w1t[j] = f2bf(W1[k * 256 + c]);
    } else if (i < 49152 + 65536) {        // W2: [128 cols x 256 k]
        int j = i - 49152 - 32768;
        int c = j >> 8, k = j & 255;
        w2t[j] = f2bf(W2[k * 128 + c]);
    } else if (i < 49152 + 65536 + 768) {
        int j = i - 49152 - 65536;
        float v;
        if (j < 128)      v = bq[j];
        else if (j < 256) v = bk[j - 128];
        else if (j < 384) v = bv[j - 256];
        else if (j < 640) v = b1[j - 384];
        else              v = b2[j - 640];
        bcat[j] = v;
    }
}

// ---- fused QKV GEMM --------------------------------------------------------
// A = x fp32 [N x 128]; blockIdx.y selects Wq/Wk/Wv.
// y=0 -> qb bf16 row-major; y=1 -> kvh k slots; y=2 -> kvh v slots.
// kvh (shorts): node s, head h: k at s*256 + h*32 + [0:16), v at +16.

__global__ __launch_bounds__(256)
void qkv_gemm_kernel(const float* __restrict__ A,
                     const unsigned short* __restrict__ wcat,
                     const float* __restrict__ bcat,
                     unsigned short* __restrict__ qb,
                     unsigned short* __restrict__ kvh,
                     int n_rows) {
    __shared__ v8s As[2048];
    __shared__ v8s Bs[2048];

    const int t = threadIdx.x;
    const int l = t & 63;
    const int w = t >> 6;
    const int mhalf = w & 1, nhalf = w >> 1;
    const int rb = blockIdx.x * 128;
    const int y  = blockIdx.y;
    const unsigned short* Bt = wcat + y * 16384;
    const float* bias = bcat + y * 128;

    v4f acc[4][4];
    #pragma unroll
    for (int i = 0; i < 4; ++i)
        #pragma unroll
        for (int j = 0; j < 4; ++j)
            acc[i][j] = (v4f){0.f, 0.f, 0.f, 0.f};

    const int r = t & 127;
    const int tile = r >> 4, m = r & 15;

    #pragma unroll
    for (int it = 0; it < 8; ++it) {
        int k8 = (t >> 7) * 8 + it * 16;
        int chunk = k8 >> 5, j = (k8 >> 3) & 3;
        int dstidx = (tile * 4 + chunk) * 64 + j * 16 + m;
        v8s av = {0, 0, 0, 0, 0, 0, 0, 0};
        if (rb + r < n_rows) {
            const float* ap = &A[(size_t)(rb + r) * 128 + k8];
            float4 f0 = *(const float4*)ap;
            float4 f1 = *(const float4*)(ap + 4);
            av[0] = (short)f2bf(f0.x); av[1] = (short)f2bf(f0.y);
            av[2] = (short)f2bf(f0.z); av[3] = (short)f2bf(f0.w);
            av[4] = (short)f2bf(f1.x); av[5] = (short)f2bf(f1.y);
            av[6] = (short)f2bf(f1.z); av[7] = (short)f2bf(f1.w);
        }
        As[dstidx] = av;
        Bs[dstidx] = *(const v8s*)&Bt[(size_t)r * 128 + k8];
    }
    __syncthreads();

    #pragma unroll
    for (int c = 0; c < 4; ++c) {
        v8s a[4], b[4];
        #pragma unroll
        for (int i = 0; i < 4; ++i)
            a[i] = As[((mhalf * 4 + i) * 4 + c) * 64 + l];
        #pragma unroll
        for (int j = 0; j < 4; ++j)
            b[j] = Bs[((nhalf * 4 + j) * 4 + c) * 64 + l];
        #pragma unroll
        for (int i = 0; i < 4; ++i)
            #pragma unroll
            for (int j = 0; j < 4; ++j)
                acc[i][j] = __builtin_amdgcn_mfma_f32_16x16x32_bf16(a[i], b[j], acc[i][j], 0, 0, 0);
    }

    const int coll = l & 15;
    #pragma unroll
    for (int i = 0; i < 4; ++i) {
        int rtile = rb + (mhalf * 4 + i) * 16 + (l >> 4) * 4;
        #pragma unroll
        for (int j = 0; j < 4; ++j) {
            int c = (nhalf * 4 + j) * 16 + coll;
            float bi = bias[c];
            #pragma unroll
            for (int reg = 0; reg < 4; ++reg) {
                int rr = rtile + reg;
                if (rr >= n_rows) continue;
                unsigned short o = f2bf(acc[i][j][reg] + bi);
                if (y == 0)
                    qb[(size_t)rr * 128 + c] = o;
                else
                    kvh[(size_t)rr * 256 + (c >> 4) * 32 + (c & 15) + (y == 2 ? 16 : 0)] = o;
            }
        }
    }
}

// ---- generic bf16 MFMA GEMM (FFN) ------------------------------------------

__global__ __launch_bounds__(256)
void mfma_gemm_kernel(const unsigned short* __restrict__ A,
                      const unsigned short* __restrict__ Bt,
                      const float* __restrict__ bias,
                      unsigned short* __restrict__ Cb,
                      float* __restrict__ Cf,
                      const float* __restrict__ resid,
                      int n_rows, int K, int ncols, int act) {
    __shared__ v8s As[2048];
    __shared__ v8s Bs[2048];

    const int t = threadIdx.x;
    const int l = t & 63;
    const int w = t >> 6;
    const int mhalf = w & 1, nhalf = w >> 1;
    const int rb = blockIdx.x * 128;
    const int cb = blockIdx.y * 128;

    v4f acc[4][4];
    #pragma unroll
    for (int i = 0; i < 4; ++i)
        #pragma unroll
        for (int j = 0; j < 4; ++j)
            acc[i][j] = (v4f){0.f, 0.f, 0.f, 0.f};

    const int r = t & 127;
    const int tile = r >> 4, m = r & 15;

    for (int kc = 0; kc < K; kc += 128) {
        #pragma unroll
        for (int it = 0; it < 8; ++it) {
            int k8 = (t >> 7) * 8 + it * 16;
            int chunk = k8 >> 5, j = (k8 >> 3) & 3;
            int dstidx = (tile * 4 + chunk) * 64 + j * 16 + m;
            v8s av = {0, 0, 0, 0, 0, 0, 0, 0};
            if (rb + r < n_rows)
                av = *(const v8s*)&A[(size_t)(rb + r) * K + kc + k8];
            As[dstidx] = av;
            Bs[dstidx] = *(const v8s*)&Bt[(size_t)(cb + r) * K + kc + k8];
        }
        __syncthreads();

        #pragma unroll
        for (int c = 0; c < 4; ++c) {
            v8s a[4], b[4];
            #pragma unroll
            for (int i = 0; i < 4; ++i)
                a[i] = As[((mhalf * 4 + i) * 4 + c) * 64 + l];
            #pragma unroll
            for (int j = 0; j < 4; ++j)
                b[j] = Bs[((nhalf * 4 + j) * 4 + c) * 64 + l];
            #pragma unroll
            for (int i = 0; i < 4; ++i)
                #pragma unroll
                for (int j = 0; j < 4; ++j)
                    acc[i][j] = __builtin_amdgcn_mfma_f32_16x16x32_bf16(a[i], b[j], acc[i][j], 0, 0, 0);
        }
        __syncthreads();
    }

    const int coll = l & 15;
    #pragma unroll
    for (int i = 0; i < 4; ++i) {
        int rtile = rb + (mhalf * 4 + i) * 16 + (l >> 4) * 4;
        #pragma unroll
        for (int j = 0; j < 4; ++j) {
            int c = cb + (nhalf * 4 + j) * 16 + coll;
            float bi = bias[c];
            #pragma unroll
            for (int reg = 0; reg < 4; ++reg) {
                int rr = rtile + reg;
                if (rr >= n_rows) continue;
                float vv = acc[i][j][reg] + bi;
                if (act) vv = gelu_exact(vv);
                if (Cf) {
                    float o = vv;
                    if (resid) o += resid[(size_t)rr * ncols + c];
                    Cf[(size_t)rr * ncols + c] = o;
                } else {
                    Cb[(size_t)rr * ncols + c] = f2bf(vv);
                }
            }
        }
    }
}

// ---- Attention + residual + LayerNorm --------------------------------------
// One wave per dst node. lane = slot*8 + head (slot = lane>>3, head = lane&7).
// Each lane processes edge (j + slot) fully in-register for its head.
// Merge across slots via reduce-scatter butterfly (NO dynamic register-array
// indexing — R4's acc[slot] forced an LDS spill).

__global__ __launch_bounds__(256)
void attn_ln_kernel(const unsigned short* __restrict__ q,
                    const unsigned short* __restrict__ kvh,
                    const float* __restrict__ x,
                    const int* __restrict__ offs, const int* __restrict__ esrc,
                    const float* __restrict__ ln_g, const float* __restrict__ ln_b,
                    float* __restrict__ hb, unsigned short* __restrict__ hnb, int n) {
    const int wave = threadIdx.x >> 6;
    const int lane = threadIdx.x & 63;
    const int node = blockIdx.x * 4 + wave;
    if (node >= n) return;
    const int head = lane & 7;
    const int slot = lane >> 3;

    const unsigned int* qp = (const unsigned int*)&q[(size_t)node * 128 + head * 16];
    float2 qv[8];
    #pragma unroll
    for (int i = 0; i < 8; ++i) qv[i] = bf2_to_f2(qp[i]);

    const int e0 = offs[node], e1 = offs[node + 1];

    float l = 0.f;
    float2 acc[8];
    #pragma unroll
    for (int i = 0; i < 8; ++i) acc[i] = make_float2(0.f, 0.f);

    if (e1 > e0) {
        for (int j = e0; j < e1; j += 8) {
            int eidx = j + slot;
            bool valid = eidx < e1;
            int s = esrc[valid ? eidx : e1 - 1];
            const uint4* kp = (const uint4*)&kvh[(size_t)s * 256 + head * 32];
            uint4 ka = kp[0], kb = kp[1], va = kp[2], vb = kp[3];

            float2 f;
            float dot = 0.f;
            f = bf2_to_f2(ka.x); dot = fmaf(f.x, qv[0].x, fmaf(f.y, qv[0].y, dot));
            f = bf2_to_f2(ka.y); dot = fmaf(f.x, qv[1].x, fmaf(f.y, qv[1].y, dot));
            f = bf2_to_f2(ka.z); dot = fmaf(f.x, qv[2].x, fmaf(f.y, qv[2].y, dot));
            f = bf2_to_f2(ka.w); dot = fmaf(f.x, qv[3].x, fmaf(f.y, qv[3].y, dot));
            f = bf2_to_f2(kb.x); dot = fmaf(f.x, qv[4].x, fmaf(f.y, qv[4].y, dot));
            f = bf2_to_f2(kb.y); dot = fmaf(f.x, qv[5].x, fmaf(f.y, qv[5].y, dot));
            f = bf2_to_f2(kb.z); dot = fmaf(f.x, qv[6].x, fmaf(f.y, qv[6].y, dot));
            f = bf2_to_f2(kb.w); dot = fmaf(f.x, qv[7].x, fmaf(f.y, qv[7].y, dot));

            float pe = valid ? __expf(dot * 0.25f) : 0.f;
            l += pe;

            f = bf2_to_f2(va.x); acc[0].x = fmaf(pe, f.x, acc[0].x); acc[0].y = fmaf(pe, f.y, acc[0].y);
            f = bf2_to_f2(va.y); acc[1].x = fmaf(pe, f.x, acc[1].x); acc[1].y = fmaf(pe, f.y, acc[1].y);
            f = bf2_to_f2(va.z); acc[2].x = fmaf(pe, f.x, acc[2].x); acc[2].y = fmaf(pe, f.y, acc[2].y);
            f = bf2_to_f2(va.w); acc[3].x = fmaf(pe, f.x, acc[3].x); acc[3].y = fmaf(pe, f.y, acc[3].y);
            f = bf2_to_f2(vb.x); acc[4].x = fmaf(pe, f.x, acc[4].x); acc[4].y = fmaf(pe, f.y, acc[4].y);
            f = bf2_to_f2(vb.y); acc[5].x = fmaf(pe, f.x, acc[5].x); acc[5].y = fmaf(pe, f.y, acc[5].y);
            f = bf2_to_f2(vb.z); acc[6].x = fmaf(pe, f.x, acc[6].x); acc[6].y = fmaf(pe, f.y, acc[6].y);
            f = bf2_to_f2(vb.w); acc[7].x = fmaf(pe, f.x, acc[7].x); acc[7].y = fmaf(pe, f.y, acc[7].y);
        }
    }

    // reduce-scatter butterfly over slot bits (lane bits 3,4,5).
    // After each level, the kept array halves; the final scalar is the
    // all-slot sum of acc[my slot]. All selections are compile-time-shaped
    // (?: on uniform-per-lane flags), so everything stays in VGPRs.
    const bool b0 = (slot & 1) != 0, b1 = (slot & 2) != 0, b2 = (slot & 4) != 0;
    float2 k0[4];
    #pragma unroll
    for (int j = 0; j < 4; ++j) {
        float2 snd = b0 ? acc[2 * j] : acc[2 * j + 1];
        float2 kp  = b0 ? acc[2 * j + 1] : acc[2 * j];
        snd.x = __shfl_xor(snd.x, 8, 64);
        snd.y = __shfl_xor(snd.y, 8, 64);
        k0[j] = make_float2(kp.x + snd.x, kp.y + snd.y);
    }
    float2 k1[2];
    #pragma unroll
    for (int j = 0; j < 2; ++j) {
        float2 snd = b1 ? k0[2 * j] : k0[2 * j + 1];
        float2 kp  = b1 ? k0[2 * j + 1] : k0[2 * j];
        snd.x = __shfl_xor(snd.x, 16, 64);
        snd.y = __shfl_xor(snd.y, 16, 64);
        k1[j] = make_float2(kp.x + snd.x, kp.y + snd.y);
    }
    {
        float2 snd = b2 ? k1[0] : k1[1];
        float2 kp  = b2 ? k1[1] : k1[0];
        snd.x = __shfl_xor(snd.x, 32, 64);
        snd.y = __shfl_xor(snd.y, 32, 64);
        k1[0] = make_float2(kp.x + snd.x, kp.y + snd.y);
    }
    float2 o = k1[0];

    l += __shfl_xor(l, 8, 64);
    l += __shfl_xor(l, 16, 64);
    l += __shfl_xor(l, 32, 64);

    float inv = 1.f / (l + 1e-16f);

    const int d = head * 16 + slot * 2;
    float2 xv = *(const float2*)&x[(size_t)node * 128 + d];
    float2 hv = make_float2(o.x * inv + xv.x, o.y * inv + xv.y);
    *(float2*)&hb[(size_t)node * 128 + d] = hv;

    float s  = hv.x + hv.y;
    float s2 = hv.x * hv.x + hv.y * hv.y;
    #pragma unroll
    for (int off = 1; off < 64; off <<= 1) {
        s  += __shfl_xor(s, off, 64);
        s2 += __shfl_xor(s2, off, 64);
    }
    float mu  = s * (1.f / 128.f);
    float var = s2 * (1.f / 128.f) - mu * mu;
    float rstd = rsqrtf(var + 1e-5f);
    float2 gv = *(const float2*)&ln_g[d];
    float2 bv = *(const float2*)&ln_b[d];
    ushort2 ob;
    ob.x = f2bf((hv.x - mu) * rstd * gv.x + bv.x);
    ob.y = f2bf((hv.y - mu) * rstd * gv.y + bv.y);
    *(ushort2*)&hnb[(size_t)node * 128 + d] = ob;
}

// ---------------------------------------------------------------------------

extern "C" void kernel_launch(void* const* d_in, const int* in_sizes, int n_in,
                              void* d_out, int out_size, void* d_ws, size_t ws_size,
                              hipStream_t stream) {
    const float* x    = (const float*)d_in[0];
    const int*   ei   = (const int*)d_in[1];
    const float* Wq   = (const float*)d_in[2];
    const float* bq   = (const float*)d_in[3];
    const float* Wk   = (const float*)d_in[4];
    const float* bk   = (const float*)d_in[5];
    const float* Wv   = (const float*)d_in[6];
    const float* bv   = (const float*)d_in[7];
    const float* ln_g = (const float*)d_in[8];
    const float* ln_b = (const float*)d_in[9];
    const float* W1   = (const float*)d_in[10];
    const float* b1   = (const float*)d_in[11];
    const float* W2   = (const float*)d_in[12];
    const float* b2   = (const float*)d_in[13];
    float* out = (float*)d_out;

    const int D = 128;
    const int N = in_sizes[0] / D;
    const int E = in_sizes[1] / 2;
    const int* src = ei;
    const int* dst = ei + E;

    const size_t ND = (size_t)N * D;
    unsigned short* qb  = (unsigned short*)d_ws;        // N*128 bf16
    unsigned short* kvh = qb + ND;                      // N*256 bf16 (k/v per head)
    float*          hb  = (float*)(kvh + 2 * ND);       // N*128 fp32
    unsigned short* hnb = (unsigned short*)(hb + ND);   // N*128 bf16
    unsigned short* wcat = hnb + ND;                    // 3*16384
    unsigned short* w1t  = wcat + 49152;                // 32768
    unsigned short* w2t  = w1t + 32768;                 // 32768
    float* bcat = (float*)(w2t + 32768);                // 768 floats
    int* cnt  = (int*)(bcat + 768);
    int* offs = cnt + N;
    int* bsum = offs + N + 1;                           // up to 256
    int* esrc = bsum + 256;                             // E ints
    unsigned short* hid = qb;                           // alias: N*256 bf16 over q+kvh

    const int nblk = (N + 255) / 256;   // 196

    // CSR build (by dst) — separate dispatches
    hipMemsetAsync(cnt, 0, sizeof(int) * N, stream);
    hist_kernel<<<(E + 255) / 256, 256, 0, stream>>>(dst, cnt, E);
    scan_blk_kernel<<<nblk, 256, 0, stream>>>(cnt, offs, bsum, N);
    scan_top_kernel<<<1, 256, 0, stream>>>(bsum, nblk);
    scan_add_kernel<<<nblk, 256, 0, stream>>>(offs, bsum, cnt, N, E);
    scatter_kernel<<<(E + 255) / 256, 256, 0, stream>>>(src, dst, cnt, esrc, E);

    // weights prep
    prep_kernel<<<(49152 + 65536 + 768 + 255) / 256, 256, 0, stream>>>(
        Wq, Wk, Wv, W1, W2, bq, bk, bv, b1, b2, wcat, w1t, w2t, bcat);

    // fused QKV projection
    const int rt = (N + 127) / 128;
    qkv_gemm_kernel<<<dim3(rt, 3), 256, 0, stream>>>(x, wcat, bcat, qb, kvh, N);

    // attention + residual + LN
    attn_ln_kernel<<<(N + 3) / 4, 256, 0, stream>>>(qb, kvh, x, offs, esrc,
                                                    ln_g, ln_b, hb, hnb, N);

    // FFN
    mfma_gemm_kernel<<<dim3(rt, 2), 256, 0, stream>>>(hnb, w1t, bcat + 384, hid,
                                                      nullptr, nullptr, N, 128, 256, 1);
    mfma_gemm_kernel<<<dim3(rt, 1), 256, 0, stream>>>(hid, w2t, bcat + 640, nullptr,
                                                      out, hb, N, 256, 128, 0);
}

// Round 7
// 365.630 us; speedup vs baseline: 1.8504x; 1.0087x over previous
//
#include <hip/hip_runtime.h>
#include <cmath>

// ---------------------------------------------------------------------------
// StructuralAttentionLayer on MI355X (gfx950)
// N=50000, E=800000, D=128, H=8, DK=16
// Round 6: dispatch-count reduction (12 -> 8): scan_top folded into scan_add,
// prep merged into hist, scatter merged into qkv; qkv stages A once (loop
// over q/k/v weight tiles). Attention unchanged from R5 (control).
// Notes carried forward: no cooperative grid.sync (~55us each); no dynamic
// register-array indexing (LDS spill).
// ---------------------------------------------------------------------------

typedef short v8s __attribute__((ext_vector_type(8)));   // 8 bf16 (4 VGPRs)
typedef float v4f __attribute__((ext_vector_type(4)));   // 4 fp32 acc

__device__ __forceinline__ float gelu_exact(float x) {
    return 0.5f * x * (1.0f + erff(x * 0.70710678118654752440f));
}

__device__ __forceinline__ unsigned short f2bf(float f) {
    unsigned int u = __float_as_uint(f);
    u = (u + 0x7fffu + ((u >> 16) & 1u)) >> 16;
    return (unsigned short)u;
}

__device__ __forceinline__ float2 bf2_to_f2(unsigned int u) {
    float2 r;
    r.x = __uint_as_float(u << 16);
    r.y = __uint_as_float(u & 0xffff0000u);
    return r;
}

// ---- hist + weight-prep (merged: disjoint block ranges) --------------------

__global__ __launch_bounds__(256)
void hist_prep_kernel(const int* __restrict__ dst, int* __restrict__ cnt, int E,
                      const float* __restrict__ Wq, const float* __restrict__ Wk,
                      const float* __restrict__ Wv, const float* __restrict__ W1,
                      const float* __restrict__ W2,
                      const float* __restrict__ bq, const float* __restrict__ bk,
                      const float* __restrict__ bv, const float* __restrict__ b1,
                      const float* __restrict__ b2,
                      unsigned short* __restrict__ wcat, unsigned short* __restrict__ w1t,
                      unsigned short* __restrict__ w2t, float* __restrict__ bcat,
                      int nhist) {
    if ((int)blockIdx.x < nhist) {
        int e = blockIdx.x * 256 + threadIdx.x;
        if (e < E) atomicAdd(&cnt[dst[e]], 1);
        return;
    }
    int i = (blockIdx.x - nhist) * 256 + threadIdx.x;
    if (i < 49152) {                       // 3 x 128x128: Wt[c][k] = W[k][c]
        int m = i >> 14, j = i & 16383;
        int c = j >> 7, k = j & 127;
        const float* W = (m == 0) ? Wq : (m == 1) ? Wk : Wv;
        wcat[i] = f2bf(W[k * 128 + c]);
    } else if (i < 49152 + 32768) {        // W1: [256 cols x 128 k]
        int j = i - 49152;
        int c = j >> 7, k = j & 127;
        w1t[j] = f2bf(W1[k * 256 + c]);
    } else if (i < 49152 + 65536) {        // W2: [128 cols x 256 k]
        int j = i - 49152 - 32768;
        int c = j >> 8, k = j & 255;
        w2t[j] = f2bf(W2[k * 128 + c]);
    } else if (i < 49152 + 65536 + 768) {
        int j = i - 49152 - 65536;
        float v;
        if (j < 128)      v = bq[j];
        else if (j < 256) v = bk[j - 128];
        else if (j < 384) v = bv[j - 256];
        else if (j < 640) v = b1[j - 384];
        else              v = b2[j - 640];
        bcat[j] = v;
    }
}

// ---- scan: block-local scan, then add (each block sums bsum itself) --------

__global__ __launch_bounds__(256)
void scan_blk_kernel(const int* __restrict__ cnt, int* __restrict__ offs,
                     int* __restrict__ bsum, int n) {
    __shared__ int ws[4];
    const int t = threadIdx.x, wid = t >> 6, lane = t & 63;
    int i = blockIdx.x * 256 + t;
    int v = (i < n) ? cnt[i] : 0;
    int incl = v;
    #pragma unroll
    for (int off = 1; off < 64; off <<= 1) {
        int u = __shfl_up(incl, off, 64);
        if (lane >= off) incl += u;
    }
    if (lane == 63) ws[wid] = incl;
    __syncthreads();
    int prefix = 0, tot = 0;
    #pragma unroll
    for (int w = 0; w < 4; ++w) {
        int s = ws[w];
        if (w < wid) prefix += s;
        tot += s;
    }
    if (i < n) offs[i] = prefix + incl - v;
    if (t == 0) bsum[blockIdx.x] = tot;
}

// Each block computes its own exclusive prefix over bsum (nblk <= 256 entries)
// with one block-reduce; replaces the separate scan_top dispatch.
__global__ __launch_bounds__(256)
void scan_add_kernel(int* __restrict__ offs, const int* __restrict__ bsum,
                     int* __restrict__ cursor, int n, int E, int nbl) {
    __shared__ int ws[4];
    const int t = threadIdx.x, wid = t >> 6, lane = t & 63;
    const int b = blockIdx.x;
    int v = (t < b && t < nbl) ? bsum[t] : 0;
    #pragma unroll
    for (int off = 1; off < 64; off <<= 1)
        v += __shfl_xor(v, off, 64);
    if (lane == 0) ws[wid] = v;
    __syncthreads();
    int prefix = ws[0] + ws[1] + ws[2] + ws[3];
    int i = b * 256 + t;
    if (i < n) {
        int o = offs[i] + prefix;
        offs[i] = o;
        cursor[i] = o;
    }
    if (i == n) offs[n] = E;
}

// ---- scatter + fused QKV GEMM (merged: disjoint block ranges) --------------
// Blocks [0, nscat): scatter src ids into CSR slots.
// Blocks [nscat, ...): QKV GEMM, A (x fp32) staged to LDS once, then loop
// over y in {q,k,v} restaging only the 32KB weight tile.
// kvh (shorts): node s, head h: k at s*256 + h*32 + [0:16), v at +16.

__global__ __launch_bounds__(256)
void scatter_qkv_kernel(const int* __restrict__ src, const int* __restrict__ dst,
                        int* __restrict__ cursor, int* __restrict__ esrc, int E,
                        const float* __restrict__ A,
                        const unsigned short* __restrict__ wcat,
                        const float* __restrict__ bcat,
                        unsigned short* __restrict__ qb,
                        unsigned short* __restrict__ kvh,
                        int n_rows, int nscat) {
    __shared__ v8s As[2048];
    __shared__ v8s Bs[2048];

    if ((int)blockIdx.x < nscat) {
        int e = blockIdx.x * 256 + threadIdx.x;
        if (e < E) {
            int p = atomicAdd(&cursor[dst[e]], 1);
            esrc[p] = src[e];
        }
        return;
    }

    const int t = threadIdx.x;
    const int l = t & 63;
    const int w = t >> 6;
    const int mhalf = w & 1, nhalf = w >> 1;
    const int rb = (blockIdx.x - nscat) * 128;

    const int r = t & 127;
    const int tile = r >> 4, m = r & 15;

    // stage A once (fp32 -> bf16 fragments)
    #pragma unroll
    for (int it = 0; it < 8; ++it) {
        int k8 = (t >> 7) * 8 + it * 16;
        int chunk = k8 >> 5, j = (k8 >> 3) & 3;
        int dstidx = (tile * 4 + chunk) * 64 + j * 16 + m;
        v8s av = {0, 0, 0, 0, 0, 0, 0, 0};
        if (rb + r < n_rows) {
            const float* ap = &A[(size_t)(rb + r) * 128 + k8];
            float4 f0 = *(const float4*)ap;
            float4 f1 = *(const float4*)(ap + 4);
            av[0] = (short)f2bf(f0.x); av[1] = (short)f2bf(f0.y);
            av[2] = (short)f2bf(f0.z); av[3] = (short)f2bf(f0.w);
            av[4] = (short)f2bf(f1.x); av[5] = (short)f2bf(f1.y);
            av[6] = (short)f2bf(f1.z); av[7] = (short)f2bf(f1.w);
        }
        As[dstidx] = av;
    }

    const int coll = l & 15;
    #pragma unroll
    for (int y = 0; y < 3; ++y) {
        const unsigned short* Bt = wcat + y * 16384;
        const float* bias = bcat + y * 128;

        // stage weight tile for this projection
        #pragma unroll
        for (int it = 0; it < 8; ++it) {
            int k8 = (t >> 7) * 8 + it * 16;
            int chunk = k8 >> 5, j = (k8 >> 3) & 3;
            int dstidx = (tile * 4 + chunk) * 64 + j * 16 + m;
            Bs[dstidx] = *(const v8s*)&Bt[(size_t)r * 128 + k8];
        }
        __syncthreads();

        v4f acc[4][4];
        #pragma unroll
        for (int i = 0; i < 4; ++i)
            #pragma unroll
            for (int j = 0; j < 4; ++j)
                acc[i][j] = (v4f){0.f, 0.f, 0.f, 0.f};

        #pragma unroll
        for (int c = 0; c < 4; ++c) {
            v8s a[4], b[4];
            #pragma unroll
            for (int i = 0; i < 4; ++i)
                a[i] = As[((mhalf * 4 + i) * 4 + c) * 64 + l];
            #pragma unroll
            for (int j = 0; j < 4; ++j)
                b[j] = Bs[((nhalf * 4 + j) * 4 + c) * 64 + l];
            #pragma unroll
            for (int i = 0; i < 4; ++i)
                #pragma unroll
                for (int j = 0; j < 4; ++j)
                    acc[i][j] = __builtin_amdgcn_mfma_f32_16x16x32_bf16(a[i], b[j], acc[i][j], 0, 0, 0);
        }

        #pragma unroll
        for (int i = 0; i < 4; ++i) {
            int rtile = rb + (mhalf * 4 + i) * 16 + (l >> 4) * 4;
            #pragma unroll
            for (int j = 0; j < 4; ++j) {
                int c = (nhalf * 4 + j) * 16 + coll;
                float bi = bias[c];
                #pragma unroll
                for (int reg = 0; reg < 4; ++reg) {
                    int rr = rtile + reg;
                    if (rr >= n_rows) continue;
                    unsigned short o = f2bf(acc[i][j][reg] + bi);
                    if (y == 0)
                        qb[(size_t)rr * 128 + c] = o;
                    else
                        kvh[(size_t)rr * 256 + (c >> 4) * 32 + (c & 15) + (y == 2 ? 16 : 0)] = o;
                }
            }
        }
        __syncthreads();   // Bs reads done before next restage
    }
}

// ---- generic bf16 MFMA GEMM (FFN) ------------------------------------------

__global__ __launch_bounds__(256)
void mfma_gemm_kernel(const unsigned short* __restrict__ A,
                      const unsigned short* __restrict__ Bt,
                      const float* __restrict__ bias,
                      unsigned short* __restrict__ Cb,
                      float* __restrict__ Cf,
                      const float* __restrict__ resid,
                      int n_rows, int K, int ncols, int act) {
    __shared__ v8s As[2048];
    __shared__ v8s Bs[2048];

    const int t = threadIdx.x;
    const int l = t & 63;
    const int w = t >> 6;
    const int mhalf = w & 1, nhalf = w >> 1;
    const int rb = blockIdx.x * 128;
    const int cb = blockIdx.y * 128;

    v4f acc[4][4];
    #pragma unroll
    for (int i = 0; i < 4; ++i)
        #pragma unroll
        for (int j = 0; j < 4; ++j)
            acc[i][j] = (v4f){0.f, 0.f, 0.f, 0.f};

    const int r = t & 127;
    const int tile = r >> 4, m = r & 15;

    for (int kc = 0; kc < K; kc += 128) {
        #pragma unroll
        for (int it = 0; it < 8; ++it) {
            int k8 = (t >> 7) * 8 + it * 16;
            int chunk = k8 >> 5, j = (k8 >> 3) & 3;
            int dstidx = (tile * 4 + chunk) * 64 + j * 16 + m;
            v8s av = {0, 0, 0, 0, 0, 0, 0, 0};
            if (rb + r < n_rows)
                av = *(const v8s*)&A[(size_t)(rb + r) * K + kc + k8];
            As[dstidx] = av;
            Bs[dstidx] = *(const v8s*)&Bt[(size_t)(cb + r) * K + kc + k8];
        }
        __syncthreads();

        #pragma unroll
        for (int c = 0; c < 4; ++c) {
            v8s a[4], b[4];
            #pragma unroll
            for (int i = 0; i < 4; ++i)
                a[i] = As[((mhalf * 4 + i) * 4 + c) * 64 + l];
            #pragma unroll
            for (int j = 0; j < 4; ++j)
                b[j] = Bs[((nhalf * 4 + j) * 4 + c) * 64 + l];
            #pragma unroll
            for (int i = 0; i < 4; ++i)
                #pragma unroll
                for (int j = 0; j < 4; ++j)
                    acc[i][j] = __builtin_amdgcn_mfma_f32_16x16x32_bf16(a[i], b[j], acc[i][j], 0, 0, 0);
        }
        __syncthreads();
    }

    const int coll = l & 15;
    #pragma unroll
    for (int i = 0; i < 4; ++i) {
        int rtile = rb + (mhalf * 4 + i) * 16 + (l >> 4) * 4;
        #pragma unroll
        for (int j = 0; j < 4; ++j) {
            int c = cb + (nhalf * 4 + j) * 16 + coll;
            float bi = bias[c];
            #pragma unroll
            for (int reg = 0; reg < 4; ++reg) {
                int rr = rtile + reg;
                if (rr >= n_rows) continue;
                float vv = acc[i][j][reg] + bi;
                if (act) vv = gelu_exact(vv);
                if (Cf) {
                    float o = vv;
                    if (resid) o += resid[(size_t)rr * ncols + c];
                    Cf[(size_t)rr * ncols + c] = o;
                } else {
                    Cb[(size_t)rr * ncols + c] = f2bf(vv);
                }
            }
        }
    }
}

// ---- Attention + residual + LayerNorm (unchanged from R5) ------------------

__global__ __launch_bounds__(256)
void attn_ln_kernel(const unsigned short* __restrict__ q,
                    const unsigned short* __restrict__ kvh,
                    const float* __restrict__ x,
                    const int* __restrict__ offs, const int* __restrict__ esrc,
                    const float* __restrict__ ln_g, const float* __restrict__ ln_b,
                    float* __restrict__ hb, unsigned short* __restrict__ hnb, int n) {
    const int wave = threadIdx.x >> 6;
    const int lane = threadIdx.x & 63;
    const int node = blockIdx.x * 4 + wave;
    if (node >= n) return;
    const int head = lane & 7;
    const int slot = lane >> 3;

    const unsigned int* qp = (const unsigned int*)&q[(size_t)node * 128 + head * 16];
    float2 qv[8];
    #pragma unroll
    for (int i = 0; i < 8; ++i) qv[i] = bf2_to_f2(qp[i]);

    const int e0 = offs[node], e1 = offs[node + 1];

    float l = 0.f;
    float2 acc[8];
    #pragma unroll
    for (int i = 0; i < 8; ++i) acc[i] = make_float2(0.f, 0.f);

    if (e1 > e0) {
        for (int j = e0; j < e1; j += 8) {
            int eidx = j + slot;
            bool valid = eidx < e1;
            int s = esrc[valid ? eidx : e1 - 1];
            const uint4* kp = (const uint4*)&kvh[(size_t)s * 256 + head * 32];
            uint4 ka = kp[0], kb = kp[1], va = kp[2], vb = kp[3];

            float2 f;
            float dot = 0.f;
            f = bf2_to_f2(ka.x); dot = fmaf(f.x, qv[0].x, fmaf(f.y, qv[0].y, dot));
            f = bf2_to_f2(ka.y); dot = fmaf(f.x, qv[1].x, fmaf(f.y, qv[1].y, dot));
            f = bf2_to_f2(ka.z); dot = fmaf(f.x, qv[2].x, fmaf(f.y, qv[2].y, dot));
            f = bf2_to_f2(ka.w); dot = fmaf(f.x, qv[3].x, fmaf(f.y, qv[3].y, dot));
            f = bf2_to_f2(kb.x); dot = fmaf(f.x, qv[4].x, fmaf(f.y, qv[4].y, dot));
            f = bf2_to_f2(kb.y); dot = fmaf(f.x, qv[5].x, fmaf(f.y, qv[5].y, dot));
            f = bf2_to_f2(kb.z); dot = fmaf(f.x, qv[6].x, fmaf(f.y, qv[6].y, dot));
            f = bf2_to_f2(kb.w); dot = fmaf(f.x, qv[7].x, fmaf(f.y, qv[7].y, dot));

            float pe = valid ? __expf(dot * 0.25f) : 0.f;
            l += pe;

            f = bf2_to_f2(va.x); acc[0].x = fmaf(pe, f.x, acc[0].x); acc[0].y = fmaf(pe, f.y, acc[0].y);
            f = bf2_to_f2(va.y); acc[1].x = fmaf(pe, f.x, acc[1].x); acc[1].y = fmaf(pe, f.y, acc[1].y);
            f = bf2_to_f2(va.z); acc[2].x = fmaf(pe, f.x, acc[2].x); acc[2].y = fmaf(pe, f.y, acc[2].y);
            f = bf2_to_f2(va.w); acc[3].x = fmaf(pe, f.x, acc[3].x); acc[3].y = fmaf(pe, f.y, acc[3].y);
            f = bf2_to_f2(vb.x); acc[4].x = fmaf(pe, f.x, acc[4].x); acc[4].y = fmaf(pe, f.y, acc[4].y);
            f = bf2_to_f2(vb.y); acc[5].x = fmaf(pe, f.x, acc[5].x); acc[5].y = fmaf(pe, f.y, acc[5].y);
            f = bf2_to_f2(vb.z); acc[6].x = fmaf(pe, f.x, acc[6].x); acc[6].y = fmaf(pe, f.y, acc[6].y);
            f = bf2_to_f2(vb.w); acc[7].x = fmaf(pe, f.x, acc[7].x); acc[7].y = fmaf(pe, f.y, acc[7].y);
        }
    }

    // reduce-scatter butterfly over slot bits (no dynamic register indexing)
    const bool b0 = (slot & 1) != 0, b1 = (slot & 2) != 0, b2 = (slot & 4) != 0;
    float2 k0[4];
    #pragma unroll
    for (int j = 0; j < 4; ++j) {
        float2 snd = b0 ? acc[2 * j] : acc[2 * j + 1];
        float2 kp  = b0 ? acc[2 * j + 1] : acc[2 * j];
        snd.x = __shfl_xor(snd.x, 8, 64);
        snd.y = __shfl_xor(snd.y, 8, 64);
        k0[j] = make_float2(kp.x + snd.x, kp.y + snd.y);
    }
    float2 k1[2];
    #pragma unroll
    for (int j = 0; j < 2; ++j) {
        float2 snd = b1 ? k0[2 * j] : k0[2 * j + 1];
        float2 kp  = b1 ? k0[2 * j + 1] : k0[2 * j];
        snd.x = __shfl_xor(snd.x, 16, 64);
        snd.y = __shfl_xor(snd.y, 16, 64);
        k1[j] = make_float2(kp.x + snd.x, kp.y + snd.y);
    }
    {
        float2 snd = b2 ? k1[0] : k1[1];
        float2 kp  = b2 ? k1[1] : k1[0];
        snd.x = __shfl_xor(snd.x, 32, 64);
        snd.y = __shfl_xor(snd.y, 32, 64);
        k1[0] = make_float2(kp.x + snd.x, kp.y + snd.y);
    }
    float2 o = k1[0];

    l += __shfl_xor(l, 8, 64);
    l += __shfl_xor(l, 16, 64);
    l += __shfl_xor(l, 32, 64);

    float inv = 1.f / (l + 1e-16f);

    const int d = head * 16 + slot * 2;
    float2 xv = *(const float2*)&x[(size_t)node * 128 + d];
    float2 hv = make_float2(o.x * inv + xv.x, o.y * inv + xv.y);
    *(float2*)&hb[(size_t)node * 128 + d] = hv;

    float s  = hv.x + hv.y;
    float s2 = hv.x * hv.x + hv.y * hv.y;
    #pragma unroll
    for (int off = 1; off < 64; off <<= 1) {
        s  += __shfl_xor(s, off, 64);
        s2 += __shfl_xor(s2, off, 64);
    }
    float mu  = s * (1.f / 128.f);
    float var = s2 * (1.f / 128.f) - mu * mu;
    float rstd = rsqrtf(var + 1e-5f);
    float2 gv = *(const float2*)&ln_g[d];
    float2 bv = *(const float2*)&ln_b[d];
    ushort2 ob;
    ob.x = f2bf((hv.x - mu) * rstd * gv.x + bv.x);
    ob.y = f2bf((hv.y - mu) * rstd * gv.y + bv.y);
    *(ushort2*)&hnb[(size_t)node * 128 + d] = ob;
}

// ---------------------------------------------------------------------------

extern "C" void kernel_launch(void* const* d_in, const int* in_sizes, int n_in,
                              void* d_out, int out_size, void* d_ws, size_t ws_size,
                              hipStream_t stream) {
    const float* x    = (const float*)d_in[0];
    const int*   ei   = (const int*)d_in[1];
    const float* Wq   = (const float*)d_in[2];
    const float* bq   = (const float*)d_in[3];
    const float* Wk   = (const float*)d_in[4];
    const float* bk   = (const float*)d_in[5];
    const float* Wv   = (const float*)d_in[6];
    const float* bv   = (const float*)d_in[7];
    const float* ln_g = (const float*)d_in[8];
    const float* ln_b = (const float*)d_in[9];
    const float* W1   = (const float*)d_in[10];
    const float* b1   = (const float*)d_in[11];
    const float* W2   = (const float*)d_in[12];
    const float* b2   = (const float*)d_in[13];
    float* out = (float*)d_out;

    const int D = 128;
    const int N = in_sizes[0] / D;
    const int E = in_sizes[1] / 2;
    const int* src = ei;
    const int* dst = ei + E;

    const size_t ND = (size_t)N * D;
    unsigned short* qb  = (unsigned short*)d_ws;        // N*128 bf16
    unsigned short* kvh = qb + ND;                      // N*256 bf16 (k/v per head)
    float*          hb  = (float*)(kvh + 2 * ND);       // N*128 fp32
    unsigned short* hnb = (unsigned short*)(hb + ND);   // N*128 bf16
    unsigned short* wcat = hnb + ND;                    // 3*16384
    unsigned short* w1t  = wcat + 49152;                // 32768
    unsigned short* w2t  = w1t + 32768;                 // 32768
    float* bcat = (float*)(w2t + 32768);                // 768 floats
    int* cnt  = (int*)(bcat + 768);
    int* offs = cnt + N;
    int* bsum = offs + N + 1;                           // up to 256
    int* esrc = bsum + 256;                             // E ints
    unsigned short* hid = qb;                           // alias: N*256 bf16 over q+kvh

    const int nblk  = (N + 255) / 256;   // 196
    const int nhist = (E + 255) / 256;   // 3125
    const int nprep = (49152 + 65536 + 768 + 255) / 256;
    const int rt    = (N + 127) / 128;   // 391

    // 1) zero degree counters
    hipMemsetAsync(cnt, 0, sizeof(int) * N, stream);
    // 2) histogram + weight prep (merged)
    hist_prep_kernel<<<nhist + nprep, 256, 0, stream>>>(
        dst, cnt, E, Wq, Wk, Wv, W1, W2, bq, bk, bv, b1, b2,
        wcat, w1t, w2t, bcat, nhist);
    // 3) block-local scan
    scan_blk_kernel<<<nblk, 256, 0, stream>>>(cnt, offs, bsum, N);
    // 4) add block prefixes (each block sums bsum itself) + init cursor
    scan_add_kernel<<<nblk, 256, 0, stream>>>(offs, bsum, cnt, N, E, nblk);
    // 5) scatter + fused QKV projection (merged)
    scatter_qkv_kernel<<<nhist + rt, 256, 0, stream>>>(
        src, dst, cnt, esrc, E, x, wcat, bcat, qb, kvh, N, nhist);
    // 6) attention + residual + LN
    attn_ln_kernel<<<(N + 3) / 4, 256, 0, stream>>>(qb, kvh, x, offs, esrc,
                                                    ln_g, ln_b, hb, hnb, N);
    // 7) FFN up (gelu) -> hid
    mfma_gemm_kernel<<<dim3(rt, 2), 256, 0, stream>>>(hnb, w1t, bcat + 384, hid,
                                                      nullptr, nullptr, N, 128, 256, 1);
    // 8) FFN down + residual -> out
    mfma_gemm_kernel<<<dim3(rt, 1), 256, 0, stream>>>(hid, w2t, bcat + 640, nullptr,
                                                      out, hb, N, 256, 128, 0);
}

// Round 8
// 334.402 us; speedup vs baseline: 2.0232x; 1.0934x over previous
//
#include <hip/hip_runtime.h>
#include <cmath>

// ---------------------------------------------------------------------------
// StructuralAttentionLayer on MI355X (gfx950)
// N=50000, E=800000, D=128, H=8, DK=16
// Round 7: un-merge scatter from qkv (R6's merge starved scatter of occupancy
// via unused 64KB LDS: 17% occ, 91us). K/V stored as OCP fp8 e4m3 (HW cvt),
// halving attention gather bytes. q stays bf16.
// Carried: no cooperative grid.sync (~55us/sync); no dynamic register-array
// indexing (LDS spill); don't merge kernels with disparate resource profiles.
// ---------------------------------------------------------------------------

typedef short v8s __attribute__((ext_vector_type(8)));   // 8 bf16 (4 VGPRs)
typedef float v4f __attribute__((ext_vector_type(4)));   // 4 fp32 acc
typedef float v2f __attribute__((ext_vector_type(2)));

__device__ __forceinline__ float gelu_exact(float x) {
    return 0.5f * x * (1.0f + erff(x * 0.70710678118654752440f));
}

__device__ __forceinline__ unsigned short f2bf(float f) {
    unsigned int u = __float_as_uint(f);
    u = (u + 0x7fffu + ((u >> 16) & 1u)) >> 16;
    return (unsigned short)u;
}

__device__ __forceinline__ float2 bf2_to_f2(unsigned int u) {
    float2 r;
    r.x = __uint_as_float(u << 16);
    r.y = __uint_as_float(u & 0xffff0000u);
    return r;
}

__device__ __forceinline__ unsigned char f2fp8(float f) {
    unsigned int p = __builtin_amdgcn_cvt_pk_fp8_f32(f, f, 0, false);
    return (unsigned char)(p & 0xffu);
}

// ---- hist + weight-prep (merged: both thin, input-only) --------------------

__global__ __launch_bounds__(256)
void hist_prep_kernel(const int* __restrict__ dst, int* __restrict__ cnt, int E,
                      const float* __restrict__ Wq, const float* __restrict__ Wk,
                      const float* __restrict__ Wv, const float* __restrict__ W1,
                      const float* __restrict__ W2,
                      const float* __restrict__ bq, const float* __restrict__ bk,
                      const float* __restrict__ bv, const float* __restrict__ b1,
                      const float* __restrict__ b2,
                      unsigned short* __restrict__ wcat, unsigned short* __restrict__ w1t,
                      unsigned short* __restrict__ w2t, float* __restrict__ bcat,
                      int nhist) {
    if ((int)blockIdx.x < nhist) {
        int e = blockIdx.x * 256 + threadIdx.x;
        if (e < E) atomicAdd(&cnt[dst[e]], 1);
        return;
    }
    int i = (blockIdx.x - nhist) * 256 + threadIdx.x;
    if (i < 49152) {                       // 3 x 128x128: Wt[c][k] = W[k][c]
        int m = i >> 14, j = i & 16383;
        int c = j >> 7, k = j & 127;
        const float* W = (m == 0) ? Wq : (m == 1) ? Wk : Wv;
        wcat[i] = f2bf(W[k * 128 + c]);
    } else if (i < 49152 + 32768) {        // W1: [256 cols x 128 k]
        int j = i - 49152;
        int c = j >> 7, k = j & 127;
        w1t[j] = f2bf(W1[k * 256 + c]);
    } else if (i < 49152 + 65536) {        // W2: [128 cols x 256 k]
        int j = i - 49152 - 32768;
        int c = j >> 8, k = j & 255;
        w2t[j] = f2bf(W2[k * 128 + c]);
    } else if (i < 49152 + 65536 + 768) {
        int j = i - 49152 - 65536;
        float v;
        if (j < 128)      v = bq[j];
        else if (j < 256) v = bk[j - 128];
        else if (j < 384) v = bv[j - 256];
        else if (j < 640) v = b1[j - 384];
        else              v = b2[j - 640];
        bcat[j] = v;
    }
}

// ---- scan ------------------------------------------------------------------

__global__ __launch_bounds__(256)
void scan_blk_kernel(const int* __restrict__ cnt, int* __restrict__ offs,
                     int* __restrict__ bsum, int n) {
    __shared__ int ws[4];
    const int t = threadIdx.x, wid = t >> 6, lane = t & 63;
    int i = blockIdx.x * 256 + t;
    int v = (i < n) ? cnt[i] : 0;
    int incl = v;
    #pragma unroll
    for (int off = 1; off < 64; off <<= 1) {
        int u = __shfl_up(incl, off, 64);
        if (lane >= off) incl += u;
    }
    if (lane == 63) ws[wid] = incl;
    __syncthreads();
    int prefix = 0, tot = 0;
    #pragma unroll
    for (int w = 0; w < 4; ++w) {
        int s = ws[w];
        if (w < wid) prefix += s;
        tot += s;
    }
    if (i < n) offs[i] = prefix + incl - v;
    if (t == 0) bsum[blockIdx.x] = tot;
}

__global__ __launch_bounds__(256)
void scan_add_kernel(int* __restrict__ offs, const int* __restrict__ bsum,
                     int* __restrict__ cursor, int n, int E, int nbl) {
    __shared__ int ws[4];
    const int t = threadIdx.x, wid = t >> 6, lane = t & 63;
    const int b = blockIdx.x;
    int v = (t < b && t < nbl) ? bsum[t] : 0;
    #pragma unroll
    for (int off = 1; off < 64; off <<= 1)
        v += __shfl_xor(v, off, 64);
    if (lane == 0) ws[wid] = v;
    __syncthreads();
    int prefix = ws[0] + ws[1] + ws[2] + ws[3];
    int i = b * 256 + t;
    if (i < n) {
        int o = offs[i] + prefix;
        offs[i] = o;
        cursor[i] = o;
    }
    if (i == n) offs[n] = E;
}

// ---- scatter (standalone: LDS-free, high occupancy) ------------------------

__global__ __launch_bounds__(256)
void scatter_kernel(const int* __restrict__ src, const int* __restrict__ dst,
                    int* __restrict__ cursor, int* __restrict__ esrc, int E) {
    int e = blockIdx.x * 256 + threadIdx.x;
    if (e < E) {
        int p = atomicAdd(&cursor[dst[e]], 1);
        esrc[p] = src[e];
    }
}

// ---- fused QKV GEMM --------------------------------------------------------
// A = x fp32 [N x 128]; stage A once, loop y over {q,k,v} weight tiles.
// y=0 -> qb bf16 row-major. y=1/2 -> kvh fp8 e4m3:
// kvh (bytes): node s, head h: k dims at s*256 + h*32 + [0:16), v at +16.

__global__ __launch_bounds__(256)
void qkv_gemm_kernel(const float* __restrict__ A,
                     const unsigned short* __restrict__ wcat,
                     const float* __restrict__ bcat,
                     unsigned short* __restrict__ qb,
                     unsigned char* __restrict__ kvh,
                     int n_rows) {
    __shared__ v8s As[2048];
    __shared__ v8s Bs[2048];

    const int t = threadIdx.x;
    const int l = t & 63;
    const int w = t >> 6;
    const int mhalf = w & 1, nhalf = w >> 1;
    const int rb = blockIdx.x * 128;

    const int r = t & 127;
    const int tile = r >> 4, m = r & 15;

    // stage A once (fp32 -> bf16 fragments)
    #pragma unroll
    for (int it = 0; it < 8; ++it) {
        int k8 = (t >> 7) * 8 + it * 16;
        int chunk = k8 >> 5, j = (k8 >> 3) & 3;
        int dstidx = (tile * 4 + chunk) * 64 + j * 16 + m;
        v8s av = {0, 0, 0, 0, 0, 0, 0, 0};
        if (rb + r < n_rows) {
            const float* ap = &A[(size_t)(rb + r) * 128 + k8];
            float4 f0 = *(const float4*)ap;
            float4 f1 = *(const float4*)(ap + 4);
            av[0] = (short)f2bf(f0.x); av[1] = (short)f2bf(f0.y);
            av[2] = (short)f2bf(f0.z); av[3] = (short)f2bf(f0.w);
            av[4] = (short)f2bf(f1.x); av[5] = (short)f2bf(f1.y);
            av[6] = (short)f2bf(f1.z); av[7] = (short)f2bf(f1.w);
        }
        As[dstidx] = av;
    }

    const int coll = l & 15;
    #pragma unroll
    for (int y = 0; y < 3; ++y) {
        const unsigned short* Bt = wcat + y * 16384;
        const float* bias = bcat + y * 128;

        #pragma unroll
        for (int it = 0; it < 8; ++it) {
            int k8 = (t >> 7) * 8 + it * 16;
            int chunk = k8 >> 5, j = (k8 >> 3) & 3;
            int dstidx = (tile * 4 + chunk) * 64 + j * 16 + m;
            Bs[dstidx] = *(const v8s*)&Bt[(size_t)r * 128 + k8];
        }
        __syncthreads();

        v4f acc[4][4];
        #pragma unroll
        for (int i = 0; i < 4; ++i)
            #pragma unroll
            for (int j = 0; j < 4; ++j)
                acc[i][j] = (v4f){0.f, 0.f, 0.f, 0.f};

        #pragma unroll
        for (int c = 0; c < 4; ++c) {
            v8s a[4], b[4];
            #pragma unroll
            for (int i = 0; i < 4; ++i)
                a[i] = As[((mhalf * 4 + i) * 4 + c) * 64 + l];
            #pragma unroll
            for (int j = 0; j < 4; ++j)
                b[j] = Bs[((nhalf * 4 + j) * 4 + c) * 64 + l];
            #pragma unroll
            for (int i = 0; i < 4; ++i)
                #pragma unroll
                for (int j = 0; j < 4; ++j)
                    acc[i][j] = __builtin_amdgcn_mfma_f32_16x16x32_bf16(a[i], b[j], acc[i][j], 0, 0, 0);
        }

        #pragma unroll
        for (int i = 0; i < 4; ++i) {
            int rtile = rb + (mhalf * 4 + i) * 16 + (l >> 4) * 4;
            #pragma unroll
            for (int j = 0; j < 4; ++j) {
                int c = (nhalf * 4 + j) * 16 + coll;
                float bi = bias[c];
                #pragma unroll
                for (int reg = 0; reg < 4; ++reg) {
                    int rr = rtile + reg;
                    if (rr >= n_rows) continue;
                    float vv = acc[i][j][reg] + bi;
                    if (y == 0)
                        qb[(size_t)rr * 128 + c] = f2bf(vv);
                    else
                        kvh[(size_t)rr * 256 + (c >> 4) * 32 + (c & 15) + (y == 2 ? 16 : 0)] = f2fp8(vv);
                }
            }
        }
        __syncthreads();   // Bs reads done before next restage
    }
}

// ---- generic bf16 MFMA GEMM (FFN) ------------------------------------------

__global__ __launch_bounds__(256)
void mfma_gemm_kernel(const unsigned short* __restrict__ A,
                      const unsigned short* __restrict__ Bt,
                      const float* __restrict__ bias,
                      unsigned short* __restrict__ Cb,
                      float* __restrict__ Cf,
                      const float* __restrict__ resid,
                      int n_rows, int K, int ncols, int act) {
    __shared__ v8s As[2048];
    __shared__ v8s Bs[2048];

    const int t = threadIdx.x;
    const int l = t & 63;
    const int w = t >> 6;
    const int mhalf = w & 1, nhalf = w >> 1;
    const int rb = blockIdx.x * 128;
    const int cb = blockIdx.y * 128;

    v4f acc[4][4];
    #pragma unroll
    for (int i = 0; i < 4; ++i)
        #pragma unroll
        for (int j = 0; j < 4; ++j)
            acc[i][j] = (v4f){0.f, 0.f, 0.f, 0.f};

    const int r = t & 127;
    const int tile = r >> 4, m = r & 15;

    for (int kc = 0; kc < K; kc += 128) {
        #pragma unroll
        for (int it = 0; it < 8; ++it) {
            int k8 = (t >> 7) * 8 + it * 16;
            int chunk = k8 >> 5, j = (k8 >> 3) & 3;
            int dstidx = (tile * 4 + chunk) * 64 + j * 16 + m;
            v8s av = {0, 0, 0, 0, 0, 0, 0, 0};
            if (rb + r < n_rows)
                av = *(const v8s*)&A[(size_t)(rb + r) * K + kc + k8];
            As[dstidx] = av;
            Bs[dstidx] = *(const v8s*)&Bt[(size_t)(cb + r) * K + kc + k8];
        }
        __syncthreads();

        #pragma unroll
        for (int c = 0; c < 4; ++c) {
            v8s a[4], b[4];
            #pragma unroll
            for (int i = 0; i < 4; ++i)
                a[i] = As[((mhalf * 4 + i) * 4 + c) * 64 + l];
            #pragma unroll
            for (int j = 0; j < 4; ++j)
                b[j] = Bs[((nhalf * 4 + j) * 4 + c) * 64 + l];
            #pragma unroll
            for (int i = 0; i < 4; ++i)
                #pragma unroll
                for (int j = 0; j < 4; ++j)
                    acc[i][j] = __builtin_amdgcn_mfma_f32_16x16x32_bf16(a[i], b[j], acc[i][j], 0, 0, 0);
        }
        __syncthreads();
    }

    const int coll = l & 15;
    #pragma unroll
    for (int i = 0; i < 4; ++i) {
        int rtile = rb + (mhalf * 4 + i) * 16 + (l >> 4) * 4;
        #pragma unroll
        for (int j = 0; j < 4; ++j) {
            int c = cb + (nhalf * 4 + j) * 16 + coll;
            float bi = bias[c];
            #pragma unroll
            for (int reg = 0; reg < 4; ++reg) {
                int rr = rtile + reg;
                if (rr >= n_rows) continue;
                float vv = acc[i][j][reg] + bi;
                if (act) vv = gelu_exact(vv);
                if (Cf) {
                    float o = vv;
                    if (resid) o += resid[(size_t)rr * ncols + c];
                    Cf[(size_t)rr * ncols + c] = o;
                } else {
                    Cb[(size_t)rr * ncols + c] = f2bf(vv);
                }
            }
        }
    }
}

// ---- Attention + residual + LayerNorm --------------------------------------
// One wave per dst node. lane = slot*8 + head. Per edge per lane: one 32B
// load (16 fp8 k + 16 fp8 v), HW fp8->f32 converts, in-lane 16-dim dot.
// Reduce-scatter butterfly across slots (no dynamic register indexing).

__global__ __launch_bounds__(256)
void attn_ln_kernel(const unsigned short* __restrict__ q,
                    const unsigned char* __restrict__ kvh,
                    const float* __restrict__ x,
                    const int* __restrict__ offs, const int* __restrict__ esrc,
                    const float* __restrict__ ln_g, const float* __restrict__ ln_b,
                    float* __restrict__ hb, unsigned short* __restrict__ hnb, int n) {
    const int wave = threadIdx.x >> 6;
    const int lane = threadIdx.x & 63;
    const int node = blockIdx.x * 4 + wave;
    if (node >= n) return;
    const int head = lane & 7;
    const int slot = lane >> 3;

    const unsigned int* qp = (const unsigned int*)&q[(size_t)node * 128 + head * 16];
    float2 qv[8];
    #pragma unroll
    for (int i = 0; i < 8; ++i) qv[i] = bf2_to_f2(qp[i]);

    const int e0 = offs[node], e1 = offs[node + 1];

    float l = 0.f;
    float2 acc[8];
    #pragma unroll
    for (int i = 0; i < 8; ++i) acc[i] = make_float2(0.f, 0.f);

    if (e1 > e0) {
        for (int j = e0; j < e1; j += 8) {
            int eidx = j + slot;
            bool valid = eidx < e1;
            int s = esrc[valid ? eidx : e1 - 1];
            const uint4* kp = (const uint4*)&kvh[(size_t)s * 256 + head * 32];
            uint4 ka = kp[0];   // 16 fp8 k
            uint4 va = kp[1];   // 16 fp8 v

            v2f f;
            float dot = 0.f;
            f = __builtin_amdgcn_cvt_pk_f32_fp8(ka.x, false); dot = fmaf(f[0], qv[0].x, fmaf(f[1], qv[0].y, dot));
            f = __builtin_amdgcn_cvt_pk_f32_fp8(ka.x, true);  dot = fmaf(f[0], qv[1].x, fmaf(f[1], qv[1].y, dot));
            f = __builtin_amdgcn_cvt_pk_f32_fp8(ka.y, false); dot = fmaf(f[0], qv[2].x, fmaf(f[1], qv[2].y, dot));
            f = __builtin_amdgcn_cvt_pk_f32_fp8(ka.y, true);  dot = fmaf(f[0], qv[3].x, fmaf(f[1], qv[3].y, dot));
            f = __builtin_amdgcn_cvt_pk_f32_fp8(ka.z, false); dot = fmaf(f[0], qv[4].x, fmaf(f[1], qv[4].y, dot));
            f = __builtin_amdgcn_cvt_pk_f32_fp8(ka.z, true);  dot = fmaf(f[0], qv[5].x, fmaf(f[1], qv[5].y, dot));
            f = __builtin_amdgcn_cvt_pk_f32_fp8(ka.w, false); dot = fmaf(f[0], qv[6].x, fmaf(f[1], qv[6].y, dot));
            f = __builtin_amdgcn_cvt_pk_f32_fp8(ka.w, true);  dot = fmaf(f[0], qv[7].x, fmaf(f[1], qv[7].y, dot));

            float pe = valid ? __expf(dot * 0.25f) : 0.f;
            l += pe;

            f = __builtin_amdgcn_cvt_pk_f32_fp8(va.x, false); acc[0].x = fmaf(pe, f[0], acc[0].x); acc[0].y = fmaf(pe, f[1], acc[0].y);
            f = __builtin_amdgcn_cvt_pk_f32_fp8(va.x, true);  acc[1].x = fmaf(pe, f[0], acc[1].x); acc[1].y = fmaf(pe, f[1], acc[1].y);
            f = __builtin_amdgcn_cvt_pk_f32_fp8(va.y, false); acc[2].x = fmaf(pe, f[0], acc[2].x); acc[2].y = fmaf(pe, f[1], acc[2].y);
            f = __builtin_amdgcn_cvt_pk_f32_fp8(va.y, true);  acc[3].x = fmaf(pe, f[0], acc[3].x); acc[3].y = fmaf(pe, f[1], acc[3].y);
            f = __builtin_amdgcn_cvt_pk_f32_fp8(va.z, false); acc[4].x = fmaf(pe, f[0], acc[4].x); acc[4].y = fmaf(pe, f[1], acc[4].y);
            f = __builtin_amdgcn_cvt_pk_f32_fp8(va.z, true);  acc[5].x = fmaf(pe, f[0], acc[5].x); acc[5].y = fmaf(pe, f[1], acc[5].y);
            f = __builtin_amdgcn_cvt_pk_f32_fp8(va.w, false); acc[6].x = fmaf(pe, f[0], acc[6].x); acc[6].y = fmaf(pe, f[1], acc[6].y);
            f = __builtin_amdgcn_cvt_pk_f32_fp8(va.w, true);  acc[7].x = fmaf(pe, f[0], acc[7].x); acc[7].y = fmaf(pe, f[1], acc[7].y);
        }
    }

    // reduce-scatter butterfly over slot bits (lane bits 3,4,5)
    const bool b0 = (slot & 1) != 0, b1 = (slot & 2) != 0, b2 = (slot & 4) != 0;
    float2 k0[4];
    #pragma unroll
    for (int j = 0; j < 4; ++j) {
        float2 snd = b0 ? acc[2 * j] : acc[2 * j + 1];
        float2 kp  = b0 ? acc[2 * j + 1] : acc[2 * j];
        snd.x = __shfl_xor(snd.x, 8, 64);
        snd.y = __shfl_xor(snd.y, 8, 64);
        k0[j] = make_float2(kp.x + snd.x, kp.y + snd.y);
    }
    float2 k1[2];
    #pragma unroll
    for (int j = 0; j < 2; ++j) {
        float2 snd = b1 ? k0[2 * j] : k0[2 * j + 1];
        float2 kp  = b1 ? k0[2 * j + 1] : k0[2 * j];
        snd.x = __shfl_xor(snd.x, 16, 64);
        snd.y = __shfl_xor(snd.y, 16, 64);
        k1[j] = make_float2(kp.x + snd.x, kp.y + snd.y);
    }
    {
        float2 snd = b2 ? k1[0] : k1[1];
        float2 kp  = b2 ? k1[1] : k1[0];
        snd.x = __shfl_xor(snd.x, 32, 64);
        snd.y = __shfl_xor(snd.y, 32, 64);
        k1[0] = make_float2(kp.x + snd.x, kp.y + snd.y);
    }
    float2 o = k1[0];

    l += __shfl_xor(l, 8, 64);
    l += __shfl_xor(l, 16, 64);
    l += __shfl_xor(l, 32, 64);

    float inv = 1.f / (l + 1e-16f);

    const int d = head * 16 + slot * 2;
    float2 xv = *(const float2*)&x[(size_t)node * 128 + d];
    float2 hv = make_float2(o.x * inv + xv.x, o.y * inv + xv.y);
    *(float2*)&hb[(size_t)node * 128 + d] = hv;

    float s  = hv.x + hv.y;
    float s2 = hv.x * hv.x + hv.y * hv.y;
    #pragma unroll
    for (int off = 1; off < 64; off <<= 1) {
        s  += __shfl_xor(s, off, 64);
        s2 += __shfl_xor(s2, off, 64);
    }
    float mu  = s * (1.f / 128.f);
    float var = s2 * (1.f / 128.f) - mu * mu;
    float rstd = rsqrtf(var + 1e-5f);
    float2 gv = *(const float2*)&ln_g[d];
    float2 bv = *(const float2*)&ln_b[d];
    ushort2 ob;
    ob.x = f2bf((hv.x - mu) * rstd * gv.x + bv.x);
    ob.y = f2bf((hv.y - mu) * rstd * gv.y + bv.y);
    *(ushort2*)&hnb[(size_t)node * 128 + d] = ob;
}

// ---------------------------------------------------------------------------

extern "C" void kernel_launch(void* const* d_in, const int* in_sizes, int n_in,
                              void* d_out, int out_size, void* d_ws, size_t ws_size,
                              hipStream_t stream) {
    const float* x    = (const float*)d_in[0];
    const int*   ei   = (const int*)d_in[1];
    const float* Wq   = (const float*)d_in[2];
    const float* bq   = (const float*)d_in[3];
    const float* Wk   = (const float*)d_in[4];
    const float* bk   = (const float*)d_in[5];
    const float* Wv   = (const float*)d_in[6];
    const float* bv   = (const float*)d_in[7];
    const float* ln_g = (const float*)d_in[8];
    const float* ln_b = (const float*)d_in[9];
    const float* W1   = (const float*)d_in[10];
    const float* b1   = (const float*)d_in[11];
    const float* W2   = (const float*)d_in[12];
    const float* b2   = (const float*)d_in[13];
    float* out = (float*)d_out;

    const int D = 128;
    const int N = in_sizes[0] / D;
    const int E = in_sizes[1] / 2;
    const int* src = ei;
    const int* dst = ei + E;

    const size_t ND = (size_t)N * D;
    unsigned short* qb  = (unsigned short*)d_ws;          // N*128 bf16
    unsigned char*  kvh = (unsigned char*)(qb + ND);      // N*256 fp8
    float*          hb  = (float*)(kvh + (size_t)N * 256);// N*128 fp32
    unsigned short* hnb = (unsigned short*)(hb + ND);     // N*128 bf16
    unsigned short* wcat = hnb + ND;                      // 3*16384
    unsigned short* w1t  = wcat + 49152;                  // 32768
    unsigned short* w2t  = w1t + 32768;                   // 32768
    float* bcat = (float*)(w2t + 32768);                  // 768 floats
    int* cnt  = (int*)(bcat + 768);
    int* offs = cnt + N;
    int* bsum = offs + N + 1;                             // up to 256
    int* esrc = bsum + 256;                               // E ints
    unsigned short* hid = qb;   // alias: N*256 bf16 over q (25.6MB) + kvh (12.8MB) region

    const int nblk  = (N + 255) / 256;   // 196
    const int nhist = (E + 255) / 256;   // 3125
    const int nprep = (49152 + 65536 + 768 + 255) / 256;
    const int rt    = (N + 127) / 128;   // 391

    // 1) zero degree counters
    hipMemsetAsync(cnt, 0, sizeof(int) * N, stream);
    // 2) histogram + weight prep (merged: both thin)
    hist_prep_kernel<<<nhist + nprep, 256, 0, stream>>>(
        dst, cnt, E, Wq, Wk, Wv, W1, W2, bq, bk, bv, b1, b2,
        wcat, w1t, w2t, bcat, nhist);
    // 3) block-local scan
    scan_blk_kernel<<<nblk, 256, 0, stream>>>(cnt, offs, bsum, N);
    // 4) add block prefixes + init cursor
    scan_add_kernel<<<nblk, 256, 0, stream>>>(offs, bsum, cnt, N, E, nblk);
    // 5) scatter (standalone — needs occupancy, not LDS)
    scatter_kernel<<<nhist, 256, 0, stream>>>(src, dst, cnt, esrc, E);
    // 6) fused QKV projection (bf16 q, fp8 k/v)
    qkv_gemm_kernel<<<rt, 256, 0, stream>>>(x, wcat, bcat, qb, kvh, N);
    // 7) attention + residual + LN
    attn_ln_kernel<<<(N + 3) / 4, 256, 0, stream>>>(qb, kvh, x, offs, esrc,
                                                    ln_g, ln_b, hb, hnb, N);
    // 8) FFN up (gelu) -> hid
    mfma_gemm_kernel<<<dim3(rt, 2), 256, 0, stream>>>(hnb, w1t, bcat + 384, hid,
                                                      nullptr, nullptr, N, 128, 256, 1);
    // 9) FFN down + residual -> out
    mfma_gemm_kernel<<<dim3(rt, 1), 256, 0, stream>>>(hid, w2t, bcat + 640, nullptr,
                                                      out, hb, N, 256, 128, 0);
}